// Round 1
// baseline (9556.293 us; speedup 1.0000x reference)
//
#include <hip/hip_runtime.h>
#include <hip/hip_bf16.h>
#include <math.h>

typedef __attribute__((ext_vector_type(8))) short short8;
typedef __attribute__((ext_vector_type(4))) float f32x4;
typedef unsigned short u16;

__device__ __forceinline__ u16 f2bf(float f) {
    union { float f; unsigned u; } v; v.f = f;
    unsigned r = v.u + 0x7fffu + ((v.u >> 16) & 1u);   // RNE
    return (u16)(r >> 16);
}
__device__ __forceinline__ float bf2f(u16 b) {
    union { unsigned u; float f; } v; v.u = ((unsigned)b) << 16;
    return v.f;
}

// ---------------- utility kernels ----------------

__global__ __launch_bounds__(256) void k_zero(unsigned* p, int n) {
    int i = blockIdx.x * 256 + threadIdx.x;
    if (i < n) p[i] = 0u;
}

__global__ __launch_bounds__(256) void k_cvt(const float* __restrict__ in,
                                             u16* __restrict__ out, int n) {
    int i = blockIdx.x * 256 + threadIdx.x;
    if (i < n) out[i] = f2bf(in[i]);
}

// W[K][N] f32 -> WT[N][K] bf16
__global__ __launch_bounds__(256) void k_transpose(const float* __restrict__ W,
                                                   u16* __restrict__ WT, int K, int N) {
    __shared__ float tile[32][33];
    int n0 = blockIdx.x * 32, k0 = blockIdx.y * 32;
    int tx = threadIdx.x & 31, ty = threadIdx.x >> 5;
    #pragma unroll
    for (int j = 0; j < 32; j += 8)
        tile[ty + j][tx] = W[(size_t)(k0 + ty + j) * N + n0 + tx];
    __syncthreads();
    #pragma unroll
    for (int j = 0; j < 32; j += 8)
        WT[(size_t)(n0 + ty + j) * K + k0 + tx] = f2bf(tile[tx][ty + j]);
}

// ---------------- generic bf16 MFMA GEMM ----------------
// C[M,N] = A[M,K] * BT[N,K]^T + bias ; MODE 0: f32 out, 1: bf16 out, 2: bf16 relu out
template <int MODE>
__global__ __launch_bounds__(256) void k_gemm(const u16* __restrict__ A,
                                              const u16* __restrict__ BT,
                                              const float* __restrict__ bias,
                                              void* __restrict__ Cout,
                                              int M, int N, int K) {
    const int w = threadIdx.x >> 6, l = threadIdx.x & 63;
    const int lm = l & 15, lq = l >> 4;
    const int r0 = blockIdx.y * 64 + w * 16;
    const int c0 = blockIdx.x * 64;
    const u16* arow = A + (size_t)(r0 + lm) * K + lq * 8;
    const u16* bp0 = BT + (size_t)(c0 + lm) * K + lq * 8;
    const u16* bp1 = bp0 + (size_t)16 * K;
    const u16* bp2 = bp0 + (size_t)32 * K;
    const u16* bp3 = bp0 + (size_t)48 * K;
    f32x4 acc0 = {0.f, 0.f, 0.f, 0.f}, acc1 = acc0, acc2 = acc0, acc3 = acc0;
    for (int k0 = 0; k0 < K; k0 += 32) {
        short8 a = *(const short8*)(arow + k0);
        acc0 = __builtin_amdgcn_mfma_f32_16x16x32_bf16(a, *(const short8*)(bp0 + k0), acc0, 0, 0, 0);
        acc1 = __builtin_amdgcn_mfma_f32_16x16x32_bf16(a, *(const short8*)(bp1 + k0), acc1, 0, 0, 0);
        acc2 = __builtin_amdgcn_mfma_f32_16x16x32_bf16(a, *(const short8*)(bp2 + k0), acc2, 0, 0, 0);
        acc3 = __builtin_amdgcn_mfma_f32_16x16x32_bf16(a, *(const short8*)(bp3 + k0), acc3, 0, 0, 0);
    }
    f32x4 accs[4] = {acc0, acc1, acc2, acc3};
    #pragma unroll
    for (int nt = 0; nt < 4; nt++) {
        #pragma unroll
        for (int r = 0; r < 4; r++) {
            int row = r0 + lq * 4 + r;          // C/D layout: row=(l>>4)*4+reg
            int col = c0 + nt * 16 + lm;        //             col=l&15
            float v = accs[nt][r] + bias[col];
            if (MODE == 0) {
                ((float*)Cout)[(size_t)row * N + col] = v;
            } else {
                if (MODE == 2) v = fmaxf(v, 0.f);
                ((u16*)Cout)[(size_t)row * N + col] = f2bf(v);
            }
        }
    }
}

// ---------------- LayerNorm + ReLU (row width 1024) ----------------
__global__ __launch_bounds__(256) void k_ln_relu(const float* __restrict__ X,
                                                 const float* __restrict__ scale,
                                                 const float* __restrict__ bias,
                                                 u16* __restrict__ Y) {
    const int N = 1024;
    size_t row = blockIdx.x;
    const float* x = X + row * N;
    float s = 0.f, ss = 0.f;
    float vals[4];
    #pragma unroll
    for (int j = 0; j < 4; j++) {
        float v = x[threadIdx.x + 256 * j];
        vals[j] = v; s += v; ss += v * v;
    }
    #pragma unroll
    for (int o = 32; o > 0; o >>= 1) { s += __shfl_down(s, o); ss += __shfl_down(ss, o); }
    __shared__ float rs[4], rss[4];
    int w = threadIdx.x >> 6;
    if ((threadIdx.x & 63) == 0) { rs[w] = s; rss[w] = ss; }
    __syncthreads();
    __shared__ float smu, sinv;
    if (threadIdx.x == 0) {
        float a = rs[0] + rs[1] + rs[2] + rs[3];
        float bq = rss[0] + rss[1] + rss[2] + rss[3];
        float mu = a * (1.f / N);
        float var = bq * (1.f / N) - mu * mu;
        smu = mu; sinv = rsqrtf(var + 1e-6f);
    }
    __syncthreads();
    float mu = smu, inv = sinv;
    #pragma unroll
    for (int j = 0; j < 4; j++) {
        int i = threadIdx.x + 256 * j;
        float v = (vals[j] - mu) * inv * scale[i] + bias[i];
        Y[row * N + i] = f2bf(fmaxf(v, 0.f));
    }
}

// ---------------- persistent LSTM scan ----------------
// 256 blocks x 256 threads; block bk owns hidden units bk*4..bk*4+3
// (16 gate columns: local col = gate*4+uu -> global col gate*1024 + bk*4 + uu).
// Wh slice LDS-resident; c in registers; h round-trips through global (bf16).
#define SCAN_BLOCKS 256
__global__ __launch_bounds__(256, 1) void k_lstm_scan(
    const u16* __restrict__ WhT,     // [4H][H] bf16
    const u16* __restrict__ Zi,      // [8192][4H] bf16, row = b*zrow_b + t*zrow_t
    const float* __restrict__ c_in,  // [B][H] f32
    u16* __restrict__ hs,            // [T+1][B][H] bf16, slot 0 pre-filled
    float* __restrict__ c_out, float* __restrict__ h_out,
    int zrow_b, int zrow_t, unsigned* ctr) {
    const int bk = blockIdx.x;
    const int tid = threadIdx.x;
    const int w = tid >> 6, l = tid & 63, lm = l & 15, lq = l >> 4;
    __shared__ u16 whs[16 * 1032];     // col-major, padded stride 1032
    __shared__ float zbuf[64 * 16];
    {   // stage Wh slice: 16 threads per column
        int lc = tid >> 4, sub = tid & 15;
        int gate = lc >> 2, uu = lc & 3;
        const u16* src = WhT + (size_t)(gate * 1024 + bk * 4 + uu) * 1024;
        u16* dst = whs + lc * 1032;
        #pragma unroll
        for (int i = 0; i < 4; i++) {
            int k = sub * 64 + i * 16;
            *(short8*)(dst + k) = *(const short8*)(src + k);
            *(short8*)(dst + k + 8) = *(const short8*)(src + k + 8);
        }
    }
    const int u = tid & 3, b = tid >> 2;
    const int gcol = bk * 4 + u;
    float c = c_in[(size_t)b * 1024 + gcol];
    __syncthreads();

    for (int t = 0; t < 128; t++) {
        const u16* hprev = hs + (size_t)t * 65536;
        const u16* arow = hprev + (size_t)(w * 16 + lm) * 1024 + lq * 8;
        const u16* brow = whs + lm * 1032 + lq * 8;
        f32x4 acc = {0.f, 0.f, 0.f, 0.f};
        #pragma unroll 4
        for (int k0 = 0; k0 < 1024; k0 += 32) {
            short8 a = *(const short8*)(arow + k0);
            short8 bb = *(const short8*)(brow + k0);
            acc = __builtin_amdgcn_mfma_f32_16x16x32_bf16(a, bb, acc, 0, 0, 0);
        }
        #pragma unroll
        for (int r = 0; r < 4; r++)
            zbuf[(w * 16 + lq * 4 + r) * 16 + lm] = acc[r];
        __syncthreads();

        size_t zr = (size_t)b * zrow_b + (size_t)t * zrow_t;
        const u16* zi = Zi + zr * 4096 + gcol;
        float gi = zbuf[b * 16 + 0  + u] + bf2f(zi[0]);
        float gf = zbuf[b * 16 + 4  + u] + bf2f(zi[1024]);
        float gg = zbuf[b * 16 + 8  + u] + bf2f(zi[2048]);
        float go = zbuf[b * 16 + 12 + u] + bf2f(zi[3072]);
        gi = 1.f / (1.f + __expf(-gi));
        gf = 1.f / (1.f + __expf(-gf));
        gg = tanhf(gg);
        go = 1.f / (1.f + __expf(-go));
        c = gf * c + gi * gg;
        float h = go * tanhf(c);
        hs[(size_t)(t + 1) * 65536 + (size_t)b * 1024 + gcol] = f2bf(h);
        if (t == 127) {
            c_out[(size_t)b * 1024 + gcol] = c;
            h_out[(size_t)b * 1024 + gcol] = h;
        }
        __syncthreads();   // zbuf reuse + all h stores issued

        // two-level device barrier: 8 group counters (128B apart) -> root
        if (tid == 0) {
            __threadfence();   // release: wbl2 so other XCDs can see our h
            unsigned gen = (unsigned)(t + 1);
            int grp = bk & 7;
            unsigned prev = __hip_atomic_fetch_add(&ctr[32 + grp * 32], 1u,
                               __ATOMIC_RELEASE, __HIP_MEMORY_SCOPE_AGENT);
            if (prev == gen * 32u - 1u)
                __hip_atomic_fetch_add(&ctr[0], 1u, __ATOMIC_RELEASE,
                                       __HIP_MEMORY_SCOPE_AGENT);
            while (__hip_atomic_load(&ctr[0], __ATOMIC_RELAXED,
                                     __HIP_MEMORY_SCOPE_AGENT) < gen * 8u)
                __builtin_amdgcn_s_sleep(2);
        }
        __syncthreads();
        __threadfence();   // acquire: invalidate L1/L2 before reading remote h
    }
}

// ---------------- logits: [8192,1024]bf16 @ WoT[32,1024]bf16 + b_out -> f32 ----------------
// A rows are t*64+b ; output index (b*128+t)*32+n
__global__ __launch_bounds__(256) void k_logits(const u16* __restrict__ Pact,
                                                const u16* __restrict__ WoT,
                                                const float* __restrict__ bout,
                                                float* __restrict__ out) {
    int r = blockIdx.x * 8 + (threadIdx.x >> 5);
    int n = threadIdx.x & 31;
    const u16* a = Pact + (size_t)r * 1024;
    const u16* wv = WoT + (size_t)n * 1024;
    float s = 0.f;
    for (int k = 0; k < 1024; k += 8) {
        short8 av = *(const short8*)(a + k);
        short8 wvv = *(const short8*)(wv + k);
        #pragma unroll
        for (int j = 0; j < 8; j++)
            s += bf2f((u16)av[j]) * bf2f((u16)wvv[j]);
    }
    int t = r >> 6, b = r & 63;
    out[((size_t)b * 128 + t) * 32 + n] = s + bout[n];
}

// ---------------- launcher ----------------
extern "C" void kernel_launch(void* const* d_in, const int* in_sizes, int n_in,
                              void* d_out, int out_size, void* d_ws, size_t ws_size,
                              hipStream_t stream) {
    const float* x      = (const float*)d_in[0];
    const float* c0     = (const float*)d_in[1];
    const float* h0     = (const float*)d_in[2];
    const float* W_pre  = (const float*)d_in[3];
    const float* b_pre  = (const float*)d_in[4];
    const float* ln_s   = (const float*)d_in[5];
    const float* ln_b   = (const float*)d_in[6];
    const float* Wi0    = (const float*)d_in[7];
    const float* Wh0    = (const float*)d_in[8];
    const float* b0     = (const float*)d_in[9];
    const float* Wi1    = (const float*)d_in[10];
    const float* Wh1    = (const float*)d_in[11];
    const float* b1     = (const float*)d_in[12];
    const float* W_post = (const float*)d_in[13];
    const float* b_post = (const float*)d_in[14];
    const float* W_out  = (const float*)d_in[15];
    const float* b_out  = (const float*)d_in[16];
    float* out = (float*)d_out;

    char* ws = (char*)d_ws;
    size_t off = 0;
    auto alloc = [&](size_t bytes) {
        void* p = ws + off;
        off += (bytes + 255) & ~(size_t)255;
        return p;
    };
    u16* WTpre  = (u16*)alloc((size_t)1024 * 512 * 2);
    u16* WTi0   = (u16*)alloc((size_t)4096 * 1024 * 2);
    u16* WTh0   = (u16*)alloc((size_t)4096 * 1024 * 2);
    u16* WTi1   = (u16*)alloc((size_t)4096 * 1024 * 2);
    u16* WTh1   = (u16*)alloc((size_t)4096 * 1024 * 2);
    u16* WTpost = (u16*)alloc((size_t)1024 * 1024 * 2);
    u16* WTout  = (u16*)alloc((size_t)32 * 1024 * 2);
    u16* Xb     = (u16*)alloc((size_t)8192 * 512 * 2);
    u16* preact = (u16*)alloc((size_t)8192 * 1024 * 2);
    u16* hs0    = (u16*)alloc((size_t)129 * 65536 * 2);
    u16* hs1    = (u16*)alloc((size_t)129 * 65536 * 2);
    u16* postact= (u16*)alloc((size_t)8192 * 1024 * 2);
    unsigned* ctr = (unsigned*)alloc(8192);
    void* unionreg = alloc((size_t)8192 * 4096 * 2); // Zi bf16 (64MB) / pre_f32 (32MB)
    float* pre_f32 = (float*)unionreg;
    u16* Zi = (u16*)unionreg;

    // init: counters + bf16 conversions
    k_zero<<<8, 256, 0, stream>>>(ctr, 2048);
    k_cvt<<<(8192 * 512) / 256, 256, 0, stream>>>(x, Xb, 8192 * 512);
    k_cvt<<<256, 256, 0, stream>>>(h0, hs0, 65536);
    k_cvt<<<256, 256, 0, stream>>>(h0 + 65536, hs1, 65536);

    // weight transpose+convert
    k_transpose<<<dim3(32, 16), 256, 0, stream>>>(W_pre, WTpre, 512, 1024);
    k_transpose<<<dim3(128, 32), 256, 0, stream>>>(Wi0, WTi0, 1024, 4096);
    k_transpose<<<dim3(128, 32), 256, 0, stream>>>(Wh0, WTh0, 1024, 4096);
    k_transpose<<<dim3(128, 32), 256, 0, stream>>>(Wi1, WTi1, 1024, 4096);
    k_transpose<<<dim3(128, 32), 256, 0, stream>>>(Wh1, WTh1, 1024, 4096);
    k_transpose<<<dim3(32, 32), 256, 0, stream>>>(W_post, WTpost, 1024, 1024);
    k_transpose<<<dim3(1, 32), 256, 0, stream>>>(W_out, WTout, 1024, 32);

    // pre: Dense + LN + relu
    k_gemm<0><<<dim3(16, 128), 256, 0, stream>>>(Xb, WTpre, b_pre, pre_f32, 8192, 1024, 512);
    k_ln_relu<<<8192, 256, 0, stream>>>(pre_f32, ln_s, ln_b, preact);

    // layer 0
    k_gemm<1><<<dim3(64, 128), 256, 0, stream>>>(preact, WTi0, b0, Zi, 8192, 4096, 1024);
    {
        const u16* WhT_ = WTh0; const u16* Zi_ = Zi; const float* cin_ = c0;
        u16* hs_ = hs0; float* cout_ = out; float* hout_ = out + 131072;
        int zb_ = 128, zt_ = 1; unsigned* ctr_ = ctr;
        void* args[] = {&WhT_, &Zi_, &cin_, &hs_, &cout_, &hout_, &zb_, &zt_, &ctr_};
        hipLaunchCooperativeKernel((void*)k_lstm_scan, dim3(SCAN_BLOCKS), dim3(256),
                                   args, 0, stream);
    }
    // layer 1
    k_gemm<1><<<dim3(64, 128), 256, 0, stream>>>(hs0 + 65536, WTi1, b1, Zi, 8192, 4096, 1024);
    {
        const u16* WhT_ = WTh1; const u16* Zi_ = Zi; const float* cin_ = c0 + 65536;
        u16* hs_ = hs1; float* cout_ = out + 65536; float* hout_ = out + 196608;
        int zb_ = 1, zt_ = 64; unsigned* ctr_ = ctr + 1024;
        void* args[] = {&WhT_, &Zi_, &cin_, &hs_, &cout_, &hout_, &zb_, &zt_, &ctr_};
        hipLaunchCooperativeKernel((void*)k_lstm_scan, dim3(SCAN_BLOCKS), dim3(256),
                                   args, 0, stream);
    }

    // post Dense+relu, then logits
    k_gemm<2><<<dim3(16, 128), 256, 0, stream>>>(hs1 + 65536, WTpost, b_post, postact,
                                                 8192, 1024, 1024);
    k_logits<<<1024, 256, 0, stream>>>(postact, WTout, b_out, out + 262144);
}

// Round 2
// 4545.701 us; speedup vs baseline: 2.1023x; 2.1023x over previous
//
#include <hip/hip_runtime.h>
#include <hip/hip_bf16.h>
#include <math.h>

typedef __attribute__((ext_vector_type(8))) short short8;
typedef __attribute__((ext_vector_type(4))) float f32x4;
typedef unsigned short u16;
typedef unsigned long long u64;

__device__ __forceinline__ u16 f2bf(float f) {
    union { float f; unsigned u; } v; v.f = f;
    unsigned r = v.u + 0x7fffu + ((v.u >> 16) & 1u);   // RNE
    return (u16)(r >> 16);
}
__device__ __forceinline__ float bf2f(u16 b) {
    union { unsigned u; float f; } v; v.u = ((unsigned)b) << 16;
    return v.f;
}

// ---------------- utility kernels ----------------

__global__ __launch_bounds__(256) void k_zero(unsigned* p, int n) {
    int i = blockIdx.x * 256 + threadIdx.x;
    if (i < n) p[i] = 0u;
}

__global__ __launch_bounds__(256) void k_cvt(const float* __restrict__ in,
                                             u16* __restrict__ out, int n) {
    int i = blockIdx.x * 256 + threadIdx.x;
    if (i < n) out[i] = f2bf(in[i]);
}

// W[K][N] f32 -> WT[N][K] bf16
__global__ __launch_bounds__(256) void k_transpose(const float* __restrict__ W,
                                                   u16* __restrict__ WT, int K, int N) {
    __shared__ float tile[32][33];
    int n0 = blockIdx.x * 32, k0 = blockIdx.y * 32;
    int tx = threadIdx.x & 31, ty = threadIdx.x >> 5;
    #pragma unroll
    for (int j = 0; j < 32; j += 8)
        tile[ty + j][tx] = W[(size_t)(k0 + ty + j) * N + n0 + tx];
    __syncthreads();
    #pragma unroll
    for (int j = 0; j < 32; j += 8)
        WT[(size_t)(n0 + ty + j) * K + k0 + tx] = f2bf(tile[tx][ty + j]);
}

// ---------------- generic bf16 MFMA GEMM ----------------
// C[M,N] = A[M,K] * BT[N,K]^T + bias ; MODE 0: f32 out, 1: bf16 out, 2: bf16 relu out
template <int MODE>
__global__ __launch_bounds__(256) void k_gemm(const u16* __restrict__ A,
                                              const u16* __restrict__ BT,
                                              const float* __restrict__ bias,
                                              void* __restrict__ Cout,
                                              int M, int N, int K) {
    const int w = threadIdx.x >> 6, l = threadIdx.x & 63;
    const int lm = l & 15, lq = l >> 4;
    const int r0 = blockIdx.y * 64 + w * 16;
    const int c0 = blockIdx.x * 64;
    const u16* arow = A + (size_t)(r0 + lm) * K + lq * 8;
    const u16* bp0 = BT + (size_t)(c0 + lm) * K + lq * 8;
    const u16* bp1 = bp0 + (size_t)16 * K;
    const u16* bp2 = bp0 + (size_t)32 * K;
    const u16* bp3 = bp0 + (size_t)48 * K;
    f32x4 acc0 = {0.f, 0.f, 0.f, 0.f}, acc1 = acc0, acc2 = acc0, acc3 = acc0;
    for (int k0 = 0; k0 < K; k0 += 32) {
        short8 a = *(const short8*)(arow + k0);
        acc0 = __builtin_amdgcn_mfma_f32_16x16x32_bf16(a, *(const short8*)(bp0 + k0), acc0, 0, 0, 0);
        acc1 = __builtin_amdgcn_mfma_f32_16x16x32_bf16(a, *(const short8*)(bp1 + k0), acc1, 0, 0, 0);
        acc2 = __builtin_amdgcn_mfma_f32_16x16x32_bf16(a, *(const short8*)(bp2 + k0), acc2, 0, 0, 0);
        acc3 = __builtin_amdgcn_mfma_f32_16x16x32_bf16(a, *(const short8*)(bp3 + k0), acc3, 0, 0, 0);
    }
    f32x4 accs[4] = {acc0, acc1, acc2, acc3};
    #pragma unroll
    for (int nt = 0; nt < 4; nt++) {
        #pragma unroll
        for (int r = 0; r < 4; r++) {
            int row = r0 + lq * 4 + r;          // C/D layout: row=(l>>4)*4+reg
            int col = c0 + nt * 16 + lm;        //             col=l&15
            float v = accs[nt][r] + bias[col];
            if (MODE == 0) {
                ((float*)Cout)[(size_t)row * N + col] = v;
            } else {
                if (MODE == 2) v = fmaxf(v, 0.f);
                ((u16*)Cout)[(size_t)row * N + col] = f2bf(v);
            }
        }
    }
}

// ---------------- LayerNorm + ReLU (row width 1024) ----------------
__global__ __launch_bounds__(256) void k_ln_relu(const float* __restrict__ X,
                                                 const float* __restrict__ scale,
                                                 const float* __restrict__ bias,
                                                 u16* __restrict__ Y) {
    const int N = 1024;
    size_t row = blockIdx.x;
    const float* x = X + row * N;
    float s = 0.f, ss = 0.f;
    float vals[4];
    #pragma unroll
    for (int j = 0; j < 4; j++) {
        float v = x[threadIdx.x + 256 * j];
        vals[j] = v; s += v; ss += v * v;
    }
    #pragma unroll
    for (int o = 32; o > 0; o >>= 1) { s += __shfl_down(s, o); ss += __shfl_down(ss, o); }
    __shared__ float rs[4], rss[4];
    int w = threadIdx.x >> 6;
    if ((threadIdx.x & 63) == 0) { rs[w] = s; rss[w] = ss; }
    __syncthreads();
    __shared__ float smu, sinv;
    if (threadIdx.x == 0) {
        float a = rs[0] + rs[1] + rs[2] + rs[3];
        float bq = rss[0] + rss[1] + rss[2] + rss[3];
        float mu = a * (1.f / N);
        float var = bq * (1.f / N) - mu * mu;
        smu = mu; sinv = rsqrtf(var + 1e-6f);
    }
    __syncthreads();
    float mu = smu, inv = sinv;
    #pragma unroll
    for (int j = 0; j < 4; j++) {
        int i = threadIdx.x + 256 * j;
        float v = (vals[j] - mu) * inv * scale[i] + bias[i];
        Y[row * N + i] = f2bf(fmaxf(v, 0.f));
    }
}

// ---------------- persistent LSTM scan ----------------
// 256 blocks x 256 threads; block bk owns hidden units bk*4..bk*4+3
// (16 gate columns: local col = gate*4+uu -> global col gate*1024 + bk*4 + uu).
// Wh slice LDS-resident; c in registers.
// Cross-block h traffic uses relaxed AGENT-scope atomics (sc0/sc1 cache-bypass:
// stores write through the non-coherent XCD L2 to MALL, loads read MALL).
// NO fences in the loop — __syncthreads' vmcnt(0) drain before s_barrier
// guarantees write-through stores have reached the coherence point.
#define SCAN_BLOCKS 256
__global__ __launch_bounds__(256, 1) void k_lstm_scan(
    const u16* __restrict__ WhT,     // [4H][H] bf16
    const u16* __restrict__ Zi,      // [8192][4H] bf16, row = b*zrow_b + t*zrow_t
    const float* __restrict__ c_in,  // [B][H] f32
    u16* __restrict__ hs,            // [T+1][B][H] bf16, slot 0 pre-filled
    float* __restrict__ c_out, float* __restrict__ h_out,
    int zrow_b, int zrow_t, unsigned* ctr) {
    const int bk = blockIdx.x;
    const int tid = threadIdx.x;
    const int w = tid >> 6, l = tid & 63, lm = l & 15, lq = l >> 4;
    __shared__ u16 whs[16 * 1032];     // col-major, padded stride 1032
    __shared__ float zbuf[64 * 16];
    {   // stage Wh slice: 16 threads per column
        int lc = tid >> 4, sub = tid & 15;
        int gate = lc >> 2, uu = lc & 3;
        const u16* src = WhT + (size_t)(gate * 1024 + bk * 4 + uu) * 1024;
        u16* dst = whs + lc * 1032;
        #pragma unroll
        for (int i = 0; i < 4; i++) {
            int k = sub * 64 + i * 16;
            *(short8*)(dst + k) = *(const short8*)(src + k);
            *(short8*)(dst + k + 8) = *(const short8*)(src + k + 8);
        }
    }
    const int u = tid & 3, b = tid >> 2;
    const int gcol = bk * 4 + u;
    float c = c_in[(size_t)b * 1024 + gcol];
    __syncthreads();

    for (int t = 0; t < 128; t++) {
        const u16* hprev = hs + (size_t)t * 65536;
        const u16* arow = hprev + (size_t)(w * 16 + lm) * 1024 + lq * 8;
        const u16* brow = whs + lm * 1032 + lq * 8;
        f32x4 acc = {0.f, 0.f, 0.f, 0.f};
        #pragma unroll 4
        for (int k0 = 0; k0 < 1024; k0 += 32) {
            union { u64 q[2]; short8 v; } au;
            au.q[0] = __hip_atomic_load((const u64*)(arow + k0),
                          __ATOMIC_RELAXED, __HIP_MEMORY_SCOPE_AGENT);
            au.q[1] = __hip_atomic_load((const u64*)(arow + k0 + 4),
                          __ATOMIC_RELAXED, __HIP_MEMORY_SCOPE_AGENT);
            short8 bb = *(const short8*)(brow + k0);
            acc = __builtin_amdgcn_mfma_f32_16x16x32_bf16(au.v, bb, acc, 0, 0, 0);
        }
        #pragma unroll
        for (int r = 0; r < 4; r++)
            zbuf[(w * 16 + lq * 4 + r) * 16 + lm] = acc[r];
        __syncthreads();

        size_t zr = (size_t)b * zrow_b + (size_t)t * zrow_t;
        const u16* zi = Zi + zr * 4096 + gcol;
        float gi = zbuf[b * 16 + 0  + u] + bf2f(zi[0]);
        float gf = zbuf[b * 16 + 4  + u] + bf2f(zi[1024]);
        float gg = zbuf[b * 16 + 8  + u] + bf2f(zi[2048]);
        float go = zbuf[b * 16 + 12 + u] + bf2f(zi[3072]);
        gi = 1.f / (1.f + __expf(-gi));
        gf = 1.f / (1.f + __expf(-gf));
        gg = tanhf(gg);
        go = 1.f / (1.f + __expf(-go));
        c = gf * c + gi * gg;
        float h = go * tanhf(c);
        // pack two adjacent bf16 (gcol even/odd = adjacent u16) into one u32
        // device-coherent write-through store
        unsigned hb = (unsigned)f2bf(h);
        unsigned other = __shfl_xor(hb, 1);
        if ((tid & 1) == 0) {
            unsigned packed = hb | (other << 16);
            unsigned* dst = (unsigned*)(hs + (size_t)(t + 1) * 65536
                                        + (size_t)b * 1024 + gcol);
            __hip_atomic_store(dst, packed, __ATOMIC_RELAXED,
                               __HIP_MEMORY_SCOPE_AGENT);
        }
        if (t == 127) {
            c_out[(size_t)b * 1024 + gcol] = c;
            h_out[(size_t)b * 1024 + gcol] = h;
        }
        __syncthreads();   // zbuf reuse + per-wave vmcnt(0) drain (h at MALL)

        // two-level device barrier: 8 group counters (128B apart) -> root
        if (tid == 0) {
            unsigned gen = (unsigned)(t + 1);
            int grp = bk & 7;
            unsigned prev = __hip_atomic_fetch_add(&ctr[32 + grp * 32], 1u,
                               __ATOMIC_RELAXED, __HIP_MEMORY_SCOPE_AGENT);
            if (prev == gen * 32u - 1u)
                __hip_atomic_fetch_add(&ctr[0], 1u, __ATOMIC_RELAXED,
                                       __HIP_MEMORY_SCOPE_AGENT);
            while (__hip_atomic_load(&ctr[0], __ATOMIC_RELAXED,
                                     __HIP_MEMORY_SCOPE_AGENT) < gen * 8u)
                __builtin_amdgcn_s_sleep(2);
        }
        __syncthreads();
    }
}

// ---------------- logits: [8192,1024]bf16 @ WoT[32,1024]bf16 + b_out -> f32 ----------------
// A rows are t*64+b ; output index (b*128+t)*32+n
__global__ __launch_bounds__(256) void k_logits(const u16* __restrict__ Pact,
                                                const u16* __restrict__ WoT,
                                                const float* __restrict__ bout,
                                                float* __restrict__ out) {
    int r = blockIdx.x * 8 + (threadIdx.x >> 5);
    int n = threadIdx.x & 31;
    const u16* a = Pact + (size_t)r * 1024;
    const u16* wv = WoT + (size_t)n * 1024;
    float s = 0.f;
    for (int k = 0; k < 1024; k += 8) {
        short8 av = *(const short8*)(a + k);
        short8 wvv = *(const short8*)(wv + k);
        #pragma unroll
        for (int j = 0; j < 8; j++)
            s += bf2f((u16)av[j]) * bf2f((u16)wvv[j]);
    }
    int t = r >> 6, b = r & 63;
    out[((size_t)b * 128 + t) * 32 + n] = s + bout[n];
}

// ---------------- launcher ----------------
extern "C" void kernel_launch(void* const* d_in, const int* in_sizes, int n_in,
                              void* d_out, int out_size, void* d_ws, size_t ws_size,
                              hipStream_t stream) {
    const float* x      = (const float*)d_in[0];
    const float* c0     = (const float*)d_in[1];
    const float* h0     = (const float*)d_in[2];
    const float* W_pre  = (const float*)d_in[3];
    const float* b_pre  = (const float*)d_in[4];
    const float* ln_s   = (const float*)d_in[5];
    const float* ln_b   = (const float*)d_in[6];
    const float* Wi0    = (const float*)d_in[7];
    const float* Wh0    = (const float*)d_in[8];
    const float* b0     = (const float*)d_in[9];
    const float* Wi1    = (const float*)d_in[10];
    const float* Wh1    = (const float*)d_in[11];
    const float* b1     = (const float*)d_in[12];
    const float* W_post = (const float*)d_in[13];
    const float* b_post = (const float*)d_in[14];
    const float* W_out  = (const float*)d_in[15];
    const float* b_out  = (const float*)d_in[16];
    float* out = (float*)d_out;

    char* ws = (char*)d_ws;
    size_t off = 0;
    auto alloc = [&](size_t bytes) {
        void* p = ws + off;
        off += (bytes + 255) & ~(size_t)255;
        return p;
    };
    u16* WTpre  = (u16*)alloc((size_t)1024 * 512 * 2);
    u16* WTi0   = (u16*)alloc((size_t)4096 * 1024 * 2);
    u16* WTh0   = (u16*)alloc((size_t)4096 * 1024 * 2);
    u16* WTi1   = (u16*)alloc((size_t)4096 * 1024 * 2);
    u16* WTh1   = (u16*)alloc((size_t)4096 * 1024 * 2);
    u16* WTpost = (u16*)alloc((size_t)1024 * 1024 * 2);
    u16* WTout  = (u16*)alloc((size_t)32 * 1024 * 2);
    u16* Xb     = (u16*)alloc((size_t)8192 * 512 * 2);
    u16* preact = (u16*)alloc((size_t)8192 * 1024 * 2);
    u16* hs0    = (u16*)alloc((size_t)129 * 65536 * 2);
    u16* hs1    = (u16*)alloc((size_t)129 * 65536 * 2);
    u16* postact= (u16*)alloc((size_t)8192 * 1024 * 2);
    unsigned* ctr = (unsigned*)alloc(8192);
    void* unionreg = alloc((size_t)8192 * 4096 * 2); // Zi bf16 (64MB) / pre_f32 (32MB)
    float* pre_f32 = (float*)unionreg;
    u16* Zi = (u16*)unionreg;

    // init: counters + bf16 conversions
    k_zero<<<8, 256, 0, stream>>>(ctr, 2048);
    k_cvt<<<(8192 * 512) / 256, 256, 0, stream>>>(x, Xb, 8192 * 512);
    k_cvt<<<256, 256, 0, stream>>>(h0, hs0, 65536);
    k_cvt<<<256, 256, 0, stream>>>(h0 + 65536, hs1, 65536);

    // weight transpose+convert
    k_transpose<<<dim3(32, 16), 256, 0, stream>>>(W_pre, WTpre, 512, 1024);
    k_transpose<<<dim3(128, 32), 256, 0, stream>>>(Wi0, WTi0, 1024, 4096);
    k_transpose<<<dim3(128, 32), 256, 0, stream>>>(Wh0, WTh0, 1024, 4096);
    k_transpose<<<dim3(128, 32), 256, 0, stream>>>(Wi1, WTi1, 1024, 4096);
    k_transpose<<<dim3(128, 32), 256, 0, stream>>>(Wh1, WTh1, 1024, 4096);
    k_transpose<<<dim3(32, 32), 256, 0, stream>>>(W_post, WTpost, 1024, 1024);
    k_transpose<<<dim3(1, 32), 256, 0, stream>>>(W_out, WTout, 1024, 32);

    // pre: Dense + LN + relu
    k_gemm<0><<<dim3(16, 128), 256, 0, stream>>>(Xb, WTpre, b_pre, pre_f32, 8192, 1024, 512);
    k_ln_relu<<<8192, 256, 0, stream>>>(pre_f32, ln_s, ln_b, preact);

    // layer 0
    k_gemm<1><<<dim3(64, 128), 256, 0, stream>>>(preact, WTi0, b0, Zi, 8192, 4096, 1024);
    {
        const u16* WhT_ = WTh0; const u16* Zi_ = Zi; const float* cin_ = c0;
        u16* hs_ = hs0; float* cout_ = out; float* hout_ = out + 131072;
        int zb_ = 128, zt_ = 1; unsigned* ctr_ = ctr;
        void* args[] = {&WhT_, &Zi_, &cin_, &hs_, &cout_, &hout_, &zb_, &zt_, &ctr_};
        hipLaunchCooperativeKernel((void*)k_lstm_scan, dim3(SCAN_BLOCKS), dim3(256),
                                   args, 0, stream);
    }
    // layer 1
    k_gemm<1><<<dim3(64, 128), 256, 0, stream>>>(hs0 + 65536, WTi1, b1, Zi, 8192, 4096, 1024);
    {
        const u16* WhT_ = WTh1; const u16* Zi_ = Zi; const float* cin_ = c0 + 65536;
        u16* hs_ = hs1; float* cout_ = out + 65536; float* hout_ = out + 196608;
        int zb_ = 1, zt_ = 64; unsigned* ctr_ = ctr + 1024;
        void* args[] = {&WhT_, &Zi_, &cin_, &hs_, &cout_, &hout_, &zb_, &zt_, &ctr_};
        hipLaunchCooperativeKernel((void*)k_lstm_scan, dim3(SCAN_BLOCKS), dim3(256),
                                   args, 0, stream);
    }

    // post Dense+relu, then logits
    k_gemm<2><<<dim3(16, 128), 256, 0, stream>>>(hs1 + 65536, WTpost, b_post, postact,
                                                 8192, 1024, 1024);
    k_logits<<<1024, 256, 0, stream>>>(postact, WTout, b_out, out + 262144);
}

// Round 3
// 3349.394 us; speedup vs baseline: 2.8531x; 1.3572x over previous
//
#include <hip/hip_runtime.h>
#include <hip/hip_bf16.h>
#include <math.h>

typedef __attribute__((ext_vector_type(8))) short short8;
typedef __attribute__((ext_vector_type(4))) float f32x4;
typedef __attribute__((ext_vector_type(4))) unsigned u32x4;
typedef unsigned short u16;
typedef unsigned long long u64;

__device__ __forceinline__ u16 f2bf(float f) {
    union { float f; unsigned u; } v; v.f = f;
    unsigned r = v.u + 0x7fffu + ((v.u >> 16) & 1u);   // RNE
    return (u16)(r >> 16);
}
__device__ __forceinline__ float bf2f(u16 b) {
    union { unsigned u; float f; } v; v.u = ((unsigned)b) << 16;
    return v.f;
}
__device__ __forceinline__ float fast_sigmoid(float x) {
    return __builtin_amdgcn_rcpf(1.f + __expf(-x));
}
__device__ __forceinline__ float fast_tanh(float x) {
    return 1.f - 2.f * __builtin_amdgcn_rcpf(1.f + __expf(2.f * x));
}
// device-coherent (MALL) pipelined 16-B load
__device__ __forceinline__ u32x4 ldg_c16(const void* p) {
    u32x4 r;
    asm volatile("global_load_dwordx4 %0, %1, off sc0 sc1"
                 : "=v"(r) : "v"(p) : "memory");
    return r;
}

// ---------------- utility kernels ----------------

__global__ __launch_bounds__(256) void k_zero(unsigned* p, int n) {
    int i = blockIdx.x * 256 + threadIdx.x;
    if (i < n) p[i] = 0u;
}

__global__ __launch_bounds__(256) void k_cvt(const float* __restrict__ in,
                                             u16* __restrict__ out, int n) {
    int i = blockIdx.x * 256 + threadIdx.x;
    if (i < n) out[i] = f2bf(in[i]);
}

// W[K][N] f32 -> WT[N][K] bf16
__global__ __launch_bounds__(256) void k_transpose(const float* __restrict__ W,
                                                   u16* __restrict__ WT, int K, int N) {
    __shared__ float tile[32][33];
    int n0 = blockIdx.x * 32, k0 = blockIdx.y * 32;
    int tx = threadIdx.x & 31, ty = threadIdx.x >> 5;
    #pragma unroll
    for (int j = 0; j < 32; j += 8)
        tile[ty + j][tx] = W[(size_t)(k0 + ty + j) * N + n0 + tx];
    __syncthreads();
    #pragma unroll
    for (int j = 0; j < 32; j += 8)
        WT[(size_t)(n0 + ty + j) * K + k0 + tx] = f2bf(tile[tx][ty + j]);
}

// ---------------- generic bf16 MFMA GEMM ----------------
// C[M,N] = A[M,K] * BT[N,K]^T + bias ; MODE 0: f32 out, 1: bf16 out, 2: bf16 relu out
template <int MODE>
__global__ __launch_bounds__(256) void k_gemm(const u16* __restrict__ A,
                                              const u16* __restrict__ BT,
                                              const float* __restrict__ bias,
                                              void* __restrict__ Cout,
                                              int M, int N, int K) {
    const int w = threadIdx.x >> 6, l = threadIdx.x & 63;
    const int lm = l & 15, lq = l >> 4;
    const int r0 = blockIdx.y * 64 + w * 16;
    const int c0 = blockIdx.x * 64;
    const u16* arow = A + (size_t)(r0 + lm) * K + lq * 8;
    const u16* bp0 = BT + (size_t)(c0 + lm) * K + lq * 8;
    const u16* bp1 = bp0 + (size_t)16 * K;
    const u16* bp2 = bp0 + (size_t)32 * K;
    const u16* bp3 = bp0 + (size_t)48 * K;
    f32x4 acc0 = {0.f, 0.f, 0.f, 0.f}, acc1 = acc0, acc2 = acc0, acc3 = acc0;
    for (int k0 = 0; k0 < K; k0 += 32) {
        short8 a = *(const short8*)(arow + k0);
        acc0 = __builtin_amdgcn_mfma_f32_16x16x32_bf16(a, *(const short8*)(bp0 + k0), acc0, 0, 0, 0);
        acc1 = __builtin_amdgcn_mfma_f32_16x16x32_bf16(a, *(const short8*)(bp1 + k0), acc1, 0, 0, 0);
        acc2 = __builtin_amdgcn_mfma_f32_16x16x32_bf16(a, *(const short8*)(bp2 + k0), acc2, 0, 0, 0);
        acc3 = __builtin_amdgcn_mfma_f32_16x16x32_bf16(a, *(const short8*)(bp3 + k0), acc3, 0, 0, 0);
    }
    f32x4 accs[4] = {acc0, acc1, acc2, acc3};
    #pragma unroll
    for (int nt = 0; nt < 4; nt++) {
        #pragma unroll
        for (int r = 0; r < 4; r++) {
            int row = r0 + lq * 4 + r;          // C/D layout: row=(l>>4)*4+reg
            int col = c0 + nt * 16 + lm;        //             col=l&15
            float v = accs[nt][r] + bias[col];
            if (MODE == 0) {
                ((float*)Cout)[(size_t)row * N + col] = v;
            } else {
                if (MODE == 2) v = fmaxf(v, 0.f);
                ((u16*)Cout)[(size_t)row * N + col] = f2bf(v);
            }
        }
    }
}

// ---------------- LayerNorm + ReLU (row width 1024) ----------------
__global__ __launch_bounds__(256) void k_ln_relu(const float* __restrict__ X,
                                                 const float* __restrict__ scale,
                                                 const float* __restrict__ bias,
                                                 u16* __restrict__ Y) {
    const int N = 1024;
    size_t row = blockIdx.x;
    const float* x = X + row * N;
    float s = 0.f, ss = 0.f;
    float vals[4];
    #pragma unroll
    for (int j = 0; j < 4; j++) {
        float v = x[threadIdx.x + 256 * j];
        vals[j] = v; s += v; ss += v * v;
    }
    #pragma unroll
    for (int o = 32; o > 0; o >>= 1) { s += __shfl_down(s, o); ss += __shfl_down(ss, o); }
    __shared__ float rs[4], rss[4];
    int w = threadIdx.x >> 6;
    if ((threadIdx.x & 63) == 0) { rs[w] = s; rss[w] = ss; }
    __syncthreads();
    __shared__ float smu, sinv;
    if (threadIdx.x == 0) {
        float a = rs[0] + rs[1] + rs[2] + rs[3];
        float bq = rss[0] + rss[1] + rss[2] + rss[3];
        float mu = a * (1.f / N);
        float var = bq * (1.f / N) - mu * mu;
        smu = mu; sinv = rsqrtf(var + 1e-6f);
    }
    __syncthreads();
    float mu = smu, inv = sinv;
    #pragma unroll
    for (int j = 0; j < 4; j++) {
        int i = threadIdx.x + 256 * j;
        float v = (vals[j] - mu) * inv * scale[i] + bias[i];
        Y[row * N + i] = f2bf(fmaxf(v, 0.f));
    }
}

// ---------------- persistent LSTM scan ----------------
// 128 blocks x 512 threads. Block bk owns hidden units bk*8..bk*8+7
// (32 gate cols). Wh slice (64KB) LDS-resident; c in registers.
// 8 waves: w = khalf*4 + rowtile; each wave computes a 16x32 z-tile over
// K-half 512 -> zero-redundancy A loads (16 coherent dwordx4 per lane,
// pipelined via inline asm + granular vmcnt pins).
// Cross-block h + barrier: relaxed agent atomics (write-through to MALL);
// slot/flag barrier (no RMW): blocks store slot[bk]=gen, block 0 polls all
// slots in parallel and publishes go=gen.
#define SCAN_BLOCKS 128
#define ZST 33
__global__ __launch_bounds__(512, 1) void k_lstm_scan(
    const u16* __restrict__ WhT,     // [4H][H] bf16
    const u16* __restrict__ Zi,      // [8192][4H] bf16, row = b*zrow_b + t*zrow_t
    const float* __restrict__ c_in,  // [B][H] f32
    u16* __restrict__ hs,            // [T+1][B][H] bf16, slot 0 pre-filled
    float* __restrict__ c_out, float* __restrict__ h_out,
    int zrow_b, int zrow_t, unsigned* ctr) {
    const int bk = blockIdx.x;
    const int tid = threadIdx.x;
    const int w = tid >> 6, l = tid & 63, lm = l & 15, lq = l >> 4;
    const int rt = w & 3, kh = w >> 2;
    __shared__ u16 whs[32 * 1032];           // 32 local gate cols x K=1024 (padded)
    __shared__ float zbuf[2 * 64 * ZST];     // [khalf][batch][32 cols] (padded)
    {   // stage Wh slice: local col lc = gate*8+u ; 16 threads per col
        int lc = tid >> 4, sub = tid & 15;
        int gate = lc >> 3, uu = lc & 7;
        const u16* src = WhT + (size_t)(gate * 1024 + bk * 8 + uu) * 1024;
        u16* dst = whs + lc * 1032;
        #pragma unroll
        for (int i = 0; i < 8; i++) {
            int k = sub * 64 + i * 8;
            *(short8*)(dst + k) = *(const short8*)(src + k);
        }
    }
    const int u = tid & 7, b = tid >> 3;
    const int gcol = bk * 8 + u;
    float c = c_in[(size_t)b * 1024 + gcol];
    __syncthreads();

    const u16* brow0 = whs + (size_t)lm * 1032 + kh * 512 + lq * 8;
    const u16* brow1 = brow0 + (size_t)16 * 1032;

    for (int t = 0; t < 128; t++) {
        // ---- prefetch Zi for this step (plain loads, in flight during MFMA)
        size_t zr = (size_t)b * zrow_b + (size_t)t * zrow_t;
        const u16* zi = Zi + zr * 4096 + gcol;
        u16 zi0 = zi[0], zi1 = zi[1024], zi2 = zi[2048], zi3 = zi[3072];

        // ---- A prefetch: 16 coherent dwordx4, fully pipelined
        const u16* arow = hs + (size_t)t * 65536
                        + (size_t)(rt * 16 + lm) * 1024 + kh * 512 + lq * 8;
        u32x4 A0 = ldg_c16(arow +   0), A1 = ldg_c16(arow +  32);
        u32x4 A2 = ldg_c16(arow +  64), A3 = ldg_c16(arow +  96);
        u32x4 A4 = ldg_c16(arow + 128), A5 = ldg_c16(arow + 160);
        u32x4 A6 = ldg_c16(arow + 192), A7 = ldg_c16(arow + 224);
        u32x4 A8 = ldg_c16(arow + 256), A9 = ldg_c16(arow + 288);
        u32x4 A10 = ldg_c16(arow + 320), A11 = ldg_c16(arow + 352);
        u32x4 A12 = ldg_c16(arow + 384), A13 = ldg_c16(arow + 416);
        u32x4 A14 = ldg_c16(arow + 448), A15 = ldg_c16(arow + 480);

        f32x4 acc0 = {0.f, 0.f, 0.f, 0.f}, acc1 = acc0;
        #define STEPI(Ai, i)                                                     \
        {   union { u32x4 q; short8 v; } _a; _a.q = (Ai);                        \
            short8 _b0 = *(const short8*)(brow0 + (i) * 32);                     \
            short8 _b1 = *(const short8*)(brow1 + (i) * 32);                     \
            acc0 = __builtin_amdgcn_mfma_f32_16x16x32_bf16(_a.v, _b0, acc0, 0, 0, 0); \
            acc1 = __builtin_amdgcn_mfma_f32_16x16x32_bf16(_a.v, _b1, acc1, 0, 0, 0); }

        asm volatile("s_waitcnt vmcnt(8)"
                     : "+v"(A0), "+v"(A1), "+v"(A2), "+v"(A3),
                       "+v"(A4), "+v"(A5), "+v"(A6), "+v"(A7) :: "memory");
        STEPI(A0, 0) STEPI(A1, 1) STEPI(A2, 2) STEPI(A3, 3)
        STEPI(A4, 4) STEPI(A5, 5) STEPI(A6, 6) STEPI(A7, 7)
        asm volatile("s_waitcnt vmcnt(0)"
                     : "+v"(A8), "+v"(A9), "+v"(A10), "+v"(A11),
                       "+v"(A12), "+v"(A13), "+v"(A14), "+v"(A15) :: "memory");
        STEPI(A8, 8) STEPI(A9, 9) STEPI(A10, 10) STEPI(A11, 11)
        STEPI(A12, 12) STEPI(A13, 13) STEPI(A14, 14) STEPI(A15, 15)
        #undef STEPI

        // z-tile -> LDS: row = rt*16 + lq*4 + r ; cols lm and 16+lm
        {
            float* zb = zbuf + (size_t)kh * 64 * ZST;
            #pragma unroll
            for (int r = 0; r < 4; r++) {
                int row = rt * 16 + lq * 4 + r;
                zb[row * ZST + lm] = acc0[r];
                zb[row * ZST + 16 + lm] = acc1[r];
            }
        }
        __syncthreads();

        // ---- gates: thread (b, u) ; local col lc = gate*8+u
        {
            const float* z0 = zbuf + (size_t)b * ZST;
            const float* z1 = z0 + (size_t)64 * ZST;
            float gi = z0[0  + u] + z1[0  + u] + bf2f(zi0);
            float gf = z0[8  + u] + z1[8  + u] + bf2f(zi1);
            float gg = z0[16 + u] + z1[16 + u] + bf2f(zi2);
            float go = z0[24 + u] + z1[24 + u] + bf2f(zi3);
            gi = fast_sigmoid(gi);
            gf = fast_sigmoid(gf);
            gg = fast_tanh(gg);
            go = fast_sigmoid(go);
            c = gf * c + gi * gg;
            float h = go * fast_tanh(c);
            // pack adjacent u16 pair into u32, write-through (agent scope)
            unsigned hb = (unsigned)f2bf(h);
            unsigned other = __shfl_xor(hb, 1);
            if ((tid & 1) == 0) {
                unsigned packed = hb | (other << 16);
                unsigned* dst = (unsigned*)(hs + (size_t)(t + 1) * 65536
                                            + (size_t)b * 1024 + gcol);
                __hip_atomic_store(dst, packed, __ATOMIC_RELAXED,
                                   __HIP_MEMORY_SCOPE_AGENT);
            }
            if (t == 127) {
                c_out[(size_t)b * 1024 + gcol] = c;
                h_out[(size_t)b * 1024 + gcol] = h;
            }
        }
        __syncthreads();   // zbuf reuse + vmcnt(0) drain: h stores at MALL

        // ---- slot/flag device barrier (no RMW)
        unsigned gen = (unsigned)(t + 1);
        if (tid == 0)
            __hip_atomic_store(&ctr[bk], gen, __ATOMIC_RELAXED,
                               __HIP_MEMORY_SCOPE_AGENT);
        if (bk == 0) {
            for (;;) {
                int ok = (tid >= SCAN_BLOCKS) ||
                         (__hip_atomic_load(&ctr[tid], __ATOMIC_RELAXED,
                                            __HIP_MEMORY_SCOPE_AGENT) >= gen);
                if (__syncthreads_count(ok) == 512) break;
            }
            if (tid == 0)
                __hip_atomic_store(&ctr[512], gen, __ATOMIC_RELAXED,
                                   __HIP_MEMORY_SCOPE_AGENT);
        } else {
            if (tid == 0) {
                while (__hip_atomic_load(&ctr[512], __ATOMIC_RELAXED,
                                         __HIP_MEMORY_SCOPE_AGENT) < gen)
                    __builtin_amdgcn_s_sleep(1);
            }
            __syncthreads();
        }
    }
}

// ---------------- logits: [8192,1024]bf16 @ WoT[32,1024]bf16 + b_out -> f32 ----------------
// A rows are t*64+b ; output index (b*128+t)*32+n
__global__ __launch_bounds__(256) void k_logits(const u16* __restrict__ Pact,
                                                const u16* __restrict__ WoT,
                                                const float* __restrict__ bout,
                                                float* __restrict__ out) {
    int r = blockIdx.x * 8 + (threadIdx.x >> 5);
    int n = threadIdx.x & 31;
    const u16* a = Pact + (size_t)r * 1024;
    const u16* wv = WoT + (size_t)n * 1024;
    float s = 0.f;
    for (int k = 0; k < 1024; k += 8) {
        short8 av = *(const short8*)(a + k);
        short8 wvv = *(const short8*)(wv + k);
        #pragma unroll
        for (int j = 0; j < 8; j++)
            s += bf2f((u16)av[j]) * bf2f((u16)wvv[j]);
    }
    int t = r >> 6, b = r & 63;
    out[((size_t)b * 128 + t) * 32 + n] = s + bout[n];
}

// ---------------- launcher ----------------
extern "C" void kernel_launch(void* const* d_in, const int* in_sizes, int n_in,
                              void* d_out, int out_size, void* d_ws, size_t ws_size,
                              hipStream_t stream) {
    const float* x      = (const float*)d_in[0];
    const float* c0     = (const float*)d_in[1];
    const float* h0     = (const float*)d_in[2];
    const float* W_pre  = (const float*)d_in[3];
    const float* b_pre  = (const float*)d_in[4];
    const float* ln_s   = (const float*)d_in[5];
    const float* ln_b   = (const float*)d_in[6];
    const float* Wi0    = (const float*)d_in[7];
    const float* Wh0    = (const float*)d_in[8];
    const float* b0     = (const float*)d_in[9];
    const float* Wi1    = (const float*)d_in[10];
    const float* Wh1    = (const float*)d_in[11];
    const float* b1     = (const float*)d_in[12];
    const float* W_post = (const float*)d_in[13];
    const float* b_post = (const float*)d_in[14];
    const float* W_out  = (const float*)d_in[15];
    const float* b_out  = (const float*)d_in[16];
    float* out = (float*)d_out;

    char* ws = (char*)d_ws;
    size_t off = 0;
    auto alloc = [&](size_t bytes) {
        void* p = ws + off;
        off += (bytes + 255) & ~(size_t)255;
        return p;
    };
    u16* WTpre  = (u16*)alloc((size_t)1024 * 512 * 2);
    u16* WTi0   = (u16*)alloc((size_t)4096 * 1024 * 2);
    u16* WTh0   = (u16*)alloc((size_t)4096 * 1024 * 2);
    u16* WTi1   = (u16*)alloc((size_t)4096 * 1024 * 2);
    u16* WTh1   = (u16*)alloc((size_t)4096 * 1024 * 2);
    u16* WTpost = (u16*)alloc((size_t)1024 * 1024 * 2);
    u16* WTout  = (u16*)alloc((size_t)32 * 1024 * 2);
    u16* Xb     = (u16*)alloc((size_t)8192 * 512 * 2);
    u16* preact = (u16*)alloc((size_t)8192 * 1024 * 2);
    u16* hs0    = (u16*)alloc((size_t)129 * 65536 * 2);
    u16* hs1    = (u16*)alloc((size_t)129 * 65536 * 2);
    u16* postact= (u16*)alloc((size_t)8192 * 1024 * 2);
    unsigned* ctr = (unsigned*)alloc(8192);
    void* unionreg = alloc((size_t)8192 * 4096 * 2); // Zi bf16 (64MB) / pre_f32 (32MB)
    float* pre_f32 = (float*)unionreg;
    u16* Zi = (u16*)unionreg;

    // init: counters + bf16 conversions
    k_zero<<<8, 256, 0, stream>>>(ctr, 2048);
    k_cvt<<<(8192 * 512) / 256, 256, 0, stream>>>(x, Xb, 8192 * 512);
    k_cvt<<<256, 256, 0, stream>>>(h0, hs0, 65536);
    k_cvt<<<256, 256, 0, stream>>>(h0 + 65536, hs1, 65536);

    // weight transpose+convert
    k_transpose<<<dim3(32, 16), 256, 0, stream>>>(W_pre, WTpre, 512, 1024);
    k_transpose<<<dim3(128, 32), 256, 0, stream>>>(Wi0, WTi0, 1024, 4096);
    k_transpose<<<dim3(128, 32), 256, 0, stream>>>(Wh0, WTh0, 1024, 4096);
    k_transpose<<<dim3(128, 32), 256, 0, stream>>>(Wi1, WTi1, 1024, 4096);
    k_transpose<<<dim3(128, 32), 256, 0, stream>>>(Wh1, WTh1, 1024, 4096);
    k_transpose<<<dim3(32, 32), 256, 0, stream>>>(W_post, WTpost, 1024, 1024);
    k_transpose<<<dim3(1, 32), 256, 0, stream>>>(W_out, WTout, 1024, 32);

    // pre: Dense + LN + relu
    k_gemm<0><<<dim3(16, 128), 256, 0, stream>>>(Xb, WTpre, b_pre, pre_f32, 8192, 1024, 512);
    k_ln_relu<<<8192, 256, 0, stream>>>(pre_f32, ln_s, ln_b, preact);

    // layer 0
    k_gemm<1><<<dim3(64, 128), 256, 0, stream>>>(preact, WTi0, b0, Zi, 8192, 4096, 1024);
    {
        const u16* WhT_ = WTh0; const u16* Zi_ = Zi; const float* cin_ = c0;
        u16* hs_ = hs0; float* cout_ = out; float* hout_ = out + 131072;
        int zb_ = 128, zt_ = 1; unsigned* ctr_ = ctr;
        void* args[] = {&WhT_, &Zi_, &cin_, &hs_, &cout_, &hout_, &zb_, &zt_, &ctr_};
        hipLaunchCooperativeKernel((void*)k_lstm_scan, dim3(SCAN_BLOCKS), dim3(512),
                                   args, 0, stream);
    }
    // layer 1
    k_gemm<1><<<dim3(64, 128), 256, 0, stream>>>(hs0 + 65536, WTi1, b1, Zi, 8192, 4096, 1024);
    {
        const u16* WhT_ = WTh1; const u16* Zi_ = Zi; const float* cin_ = c0 + 65536;
        u16* hs_ = hs1; float* cout_ = out + 65536; float* hout_ = out + 196608;
        int zb_ = 1, zt_ = 64; unsigned* ctr_ = ctr + 1024;
        void* args[] = {&WhT_, &Zi_, &cin_, &hs_, &cout_, &hout_, &zb_, &zt_, &ctr_};
        hipLaunchCooperativeKernel((void*)k_lstm_scan, dim3(SCAN_BLOCKS), dim3(512),
                                   args, 0, stream);
    }

    // post Dense+relu, then logits
    k_gemm<2><<<dim3(16, 128), 256, 0, stream>>>(hs1 + 65536, WTpost, b_post, postact,
                                                 8192, 1024, 1024);
    k_logits<<<1024, 256, 0, stream>>>(postact, WTout, b_out, out + 262144);
}

// Round 4
// 2340.182 us; speedup vs baseline: 4.0836x; 1.4313x over previous
//
#include <hip/hip_runtime.h>
#include <hip/hip_bf16.h>
#include <math.h>

typedef __attribute__((ext_vector_type(8))) short short8;
typedef __attribute__((ext_vector_type(4))) float f32x4;
typedef __attribute__((ext_vector_type(4))) unsigned u32x4;
typedef unsigned short u16;
typedef unsigned long long u64;

__device__ __forceinline__ u16 f2bf(float f) {
    union { float f; unsigned u; } v; v.f = f;
    unsigned r = v.u + 0x7fffu + ((v.u >> 16) & 1u);   // RNE
    return (u16)(r >> 16);
}
__device__ __forceinline__ float bf2f(u16 b) {
    union { unsigned u; float f; } v; v.u = ((unsigned)b) << 16;
    return v.f;
}
__device__ __forceinline__ float fast_sigmoid(float x) {
    return __builtin_amdgcn_rcpf(1.f + __expf(-x));
}
__device__ __forceinline__ float fast_tanh(float x) {
    return 1.f - 2.f * __builtin_amdgcn_rcpf(1.f + __expf(2.f * x));
}
// device-coherent (MALL) pipelined 16-B load
__device__ __forceinline__ u32x4 ldg_c16(const void* p) {
    u32x4 r;
    asm volatile("global_load_dwordx4 %0, %1, off sc0 sc1"
                 : "=v"(r) : "v"(p) : "memory");
    return r;
}

// ---------------- utility kernels ----------------

__global__ __launch_bounds__(256) void k_zero(unsigned* p, int n) {
    int i = blockIdx.x * 256 + threadIdx.x;
    if (i < n) p[i] = 0u;
}

__global__ __launch_bounds__(256) void k_cvt(const float* __restrict__ in,
                                             u16* __restrict__ out, int n) {
    int i = blockIdx.x * 256 + threadIdx.x;
    if (i < n) out[i] = f2bf(in[i]);
}

// W[K][N] f32 -> WT[N][K] bf16
__global__ __launch_bounds__(256) void k_transpose(const float* __restrict__ W,
                                                   u16* __restrict__ WT, int K, int N) {
    __shared__ float tile[32][33];
    int n0 = blockIdx.x * 32, k0 = blockIdx.y * 32;
    int tx = threadIdx.x & 31, ty = threadIdx.x >> 5;
    #pragma unroll
    for (int j = 0; j < 32; j += 8)
        tile[ty + j][tx] = W[(size_t)(k0 + ty + j) * N + n0 + tx];
    __syncthreads();
    #pragma unroll
    for (int j = 0; j < 32; j += 8)
        WT[(size_t)(n0 + ty + j) * K + k0 + tx] = f2bf(tile[tx][ty + j]);
}

// ---------------- generic bf16 MFMA GEMM ----------------
// C[M,N] = A[M,K] * BT[N,K]^T + bias ; MODE 0: f32 out, 1: bf16 out, 2: bf16 relu out
template <int MODE>
__global__ __launch_bounds__(256) void k_gemm(const u16* __restrict__ A,
                                              const u16* __restrict__ BT,
                                              const float* __restrict__ bias,
                                              void* __restrict__ Cout,
                                              int M, int N, int K) {
    const int w = threadIdx.x >> 6, l = threadIdx.x & 63;
    const int lm = l & 15, lq = l >> 4;
    const int r0 = blockIdx.y * 64 + w * 16;
    const int c0 = blockIdx.x * 64;
    const u16* arow = A + (size_t)(r0 + lm) * K + lq * 8;
    const u16* bp0 = BT + (size_t)(c0 + lm) * K + lq * 8;
    const u16* bp1 = bp0 + (size_t)16 * K;
    const u16* bp2 = bp0 + (size_t)32 * K;
    const u16* bp3 = bp0 + (size_t)48 * K;
    f32x4 acc0 = {0.f, 0.f, 0.f, 0.f}, acc1 = acc0, acc2 = acc0, acc3 = acc0;
    for (int k0 = 0; k0 < K; k0 += 32) {
        short8 a = *(const short8*)(arow + k0);
        acc0 = __builtin_amdgcn_mfma_f32_16x16x32_bf16(a, *(const short8*)(bp0 + k0), acc0, 0, 0, 0);
        acc1 = __builtin_amdgcn_mfma_f32_16x16x32_bf16(a, *(const short8*)(bp1 + k0), acc1, 0, 0, 0);
        acc2 = __builtin_amdgcn_mfma_f32_16x16x32_bf16(a, *(const short8*)(bp2 + k0), acc2, 0, 0, 0);
        acc3 = __builtin_amdgcn_mfma_f32_16x16x32_bf16(a, *(const short8*)(bp3 + k0), acc3, 0, 0, 0);
    }
    f32x4 accs[4] = {acc0, acc1, acc2, acc3};
    #pragma unroll
    for (int nt = 0; nt < 4; nt++) {
        #pragma unroll
        for (int r = 0; r < 4; r++) {
            int row = r0 + lq * 4 + r;          // C/D layout: row=(l>>4)*4+reg
            int col = c0 + nt * 16 + lm;        //             col=l&15
            float v = accs[nt][r] + bias[col];
            if (MODE == 0) {
                ((float*)Cout)[(size_t)row * N + col] = v;
            } else {
                if (MODE == 2) v = fmaxf(v, 0.f);
                ((u16*)Cout)[(size_t)row * N + col] = f2bf(v);
            }
        }
    }
}

// ---------------- LayerNorm + ReLU (row width 1024) ----------------
__global__ __launch_bounds__(256) void k_ln_relu(const float* __restrict__ X,
                                                 const float* __restrict__ scale,
                                                 const float* __restrict__ bias,
                                                 u16* __restrict__ Y) {
    const int N = 1024;
    size_t row = blockIdx.x;
    const float* x = X + row * N;
    float s = 0.f, ss = 0.f;
    float vals[4];
    #pragma unroll
    for (int j = 0; j < 4; j++) {
        float v = x[threadIdx.x + 256 * j];
        vals[j] = v; s += v; ss += v * v;
    }
    #pragma unroll
    for (int o = 32; o > 0; o >>= 1) { s += __shfl_down(s, o); ss += __shfl_down(ss, o); }
    __shared__ float rs[4], rss[4];
    int w = threadIdx.x >> 6;
    if ((threadIdx.x & 63) == 0) { rs[w] = s; rss[w] = ss; }
    __syncthreads();
    __shared__ float smu, sinv;
    if (threadIdx.x == 0) {
        float a = rs[0] + rs[1] + rs[2] + rs[3];
        float bq = rss[0] + rss[1] + rss[2] + rss[3];
        float mu = a * (1.f / N);
        float var = bq * (1.f / N) - mu * mu;
        smu = mu; sinv = rsqrtf(var + 1e-6f);
    }
    __syncthreads();
    float mu = smu, inv = sinv;
    #pragma unroll
    for (int j = 0; j < 4; j++) {
        int i = threadIdx.x + 256 * j;
        float v = (vals[j] - mu) * inv * scale[i] + bias[i];
        Y[row * N + i] = f2bf(fmaxf(v, 0.f));
    }
}

// ---------------- fused 2-layer persistent LSTM scan ----------------
// 256 blocks x 512 threads, 1 block/CU (LDS-limited), software-pipelined:
//   blocks 0..127   = layer 0, at global step s compute h0_s   (s=0..127)
//   blocks 128..255 = layer 1, at global step s compute h1_{s-1} (s=1..128)
// Both roles consume hs0 slot s (h0_{s-1}); layer 1 additionally consumes
// hs1 slot s-1 and keeps concat(Wi1,Wh1) LDS-resident (z1 = [h0;h1]@[Wi1;Wh1]+b1),
// eliminating the separate Zi1 GEMM and the second scan kernel.
// B is stored in MFMA-fragment order: frag(kp,grp,i,lq,lm) at linear offset
// -> lane-linear 16B ds_read_b128, conflict-free.
// Cross-block h: sc0/sc1 write-through stores + coherent loads (MALL).
// Barrier: one-hop all-poll-all — block stores slot[bk], every block's threads
// poll all 256 slots in parallel via __syncthreads_count.
#define FBLOCKS 256
__global__ __launch_bounds__(512, 1) void k_lstm_fused(
    const u16* __restrict__ WhT0, const u16* __restrict__ WiT1,
    const u16* __restrict__ WhT1, const u16* __restrict__ Zi0,
    const float* __restrict__ b1v, const float* __restrict__ c0_all,
    u16* __restrict__ hs0, u16* __restrict__ hs1,
    float* __restrict__ out, unsigned* __restrict__ ctr) {
    const int bk = blockIdx.x;
    const int role = bk >> 7;          // 0: layer0, 1: layer1
    const int bkl = bk & 127;
    const int tid = threadIdx.x;
    const int w = tid >> 6, l = tid & 63, lm = l & 15, lq = l >> 4;
    const int kp = w >> 2, rt = w & 3;

    __shared__ u16 whs[65536];          // 128 KB fragment-ordered B
    __shared__ float zbuf[2 * 64 * 33]; // [kp][batch][32 cols]

    // ---- stage B slices in fragment order (linear: dst = whs + f*8)
    {
        const int NI = role ? 32 : 16;
        const int F = role ? 8192 : 4096;
        const int ISH = role ? 5 : 4;
        for (int f = tid; f < F; f += 512) {
            int flm = f & 15, flq = (f >> 4) & 3;
            int fi = (f >> 6) & (NI - 1);
            int rest = f >> (6 + ISH);
            int fg = rest & 1, fkp = (rest >> 1) & 1;
            int lc = fg * 16 + flm;
            int gcolw = (lc >> 3) * 1024 + bkl * 8 + (lc & 7);
            int k = fi * 32 + flq * 8;
            const u16* src = role
                ? ((fkp == 0 ? WiT1 : WhT1) + (size_t)gcolw * 1024 + k)
                : (WhT0 + (size_t)gcolw * 1024 + fkp * 512 + k);
            *(short8*)(whs + (size_t)f * 8) = *(const short8*)src;
        }
    }
    const int u = tid & 7, b = tid >> 3;
    const int gcol = bkl * 8 + u;
    float c = (c0_all + (size_t)role * 65536)[(size_t)b * 1024 + gcol];
    float bi0 = 0.f, bi1 = 0.f, bi2 = 0.f, bi3 = 0.f;
    if (role) {
        bi0 = b1v[gcol]; bi1 = b1v[1024 + gcol];
        bi2 = b1v[2048 + gcol]; bi3 = b1v[3072 + gcol];
    }
    u16* hs_my = role ? hs1 : hs0;
    float* c_out = out + (size_t)role * 65536;
    float* h_out = out + 131072 + (size_t)role * 65536;
    // per-wave LDS base: frag(kp,grp,i) at ((kp*2+grp)*NI + i)*512 + (lq*16+lm)*8
    const int lanoff = (lq * 16 + lm) * 8;
    __syncthreads();

    for (int s = 0; s <= 128; s++) {
        const bool active = role ? (s >= 1) : (s <= 127);
        if (active) {
            const int t = role ? (s - 1) : s;
            u16 zi0v = 0, zi1v = 0, zi2v = 0, zi3v = 0;
            f32x4 acc0 = {0.f, 0.f, 0.f, 0.f}, acc1 = acc0;

            #define STEPF(Ai, i, NI)                                                  \
            {   union { u32x4 q; short8 v; } _a; _a.q = (Ai);                         \
                short8 _b0 = *(const short8*)(bw0 + (i) * 512);                       \
                short8 _b1 = *(const short8*)(bw0 + (NI) * 512 + (i) * 512);          \
                acc0 = __builtin_amdgcn_mfma_f32_16x16x32_bf16(_a.v, _b0, acc0, 0, 0, 0); \
                acc1 = __builtin_amdgcn_mfma_f32_16x16x32_bf16(_a.v, _b1, acc1, 0, 0, 0); }

            if (!role) {
                // Zi prefetch (plain cached loads, in flight during A loads)
                const u16* zi = Zi0 + ((size_t)b * 128 + t) * 4096 + gcol;
                zi0v = zi[0]; zi1v = zi[1024]; zi2v = zi[2048]; zi3v = zi[3072];
                const u16* arow = hs0 + (size_t)s * 65536
                                + (size_t)(rt * 16 + lm) * 1024 + kp * 512 + lq * 8;
                const u16* bw0 = whs + kp * 16384 + lanoff;
                u32x4 A0 = ldg_c16(arow +   0), A1 = ldg_c16(arow +  32);
                u32x4 A2 = ldg_c16(arow +  64), A3 = ldg_c16(arow +  96);
                u32x4 A4 = ldg_c16(arow + 128), A5 = ldg_c16(arow + 160);
                u32x4 A6 = ldg_c16(arow + 192), A7 = ldg_c16(arow + 224);
                u32x4 A8 = ldg_c16(arow + 256), A9 = ldg_c16(arow + 288);
                u32x4 A10 = ldg_c16(arow + 320), A11 = ldg_c16(arow + 352);
                u32x4 A12 = ldg_c16(arow + 384), A13 = ldg_c16(arow + 416);
                u32x4 A14 = ldg_c16(arow + 448), A15 = ldg_c16(arow + 480);
                asm volatile("s_waitcnt vmcnt(8)"
                             : "+v"(A0), "+v"(A1), "+v"(A2), "+v"(A3),
                               "+v"(A4), "+v"(A5), "+v"(A6), "+v"(A7) :: "memory");
                STEPF(A0, 0, 16) STEPF(A1, 1, 16) STEPF(A2, 2, 16) STEPF(A3, 3, 16)
                STEPF(A4, 4, 16) STEPF(A5, 5, 16) STEPF(A6, 6, 16) STEPF(A7, 7, 16)
                asm volatile("s_waitcnt vmcnt(0)"
                             : "+v"(A8), "+v"(A9), "+v"(A10), "+v"(A11),
                               "+v"(A12), "+v"(A13), "+v"(A14), "+v"(A15) :: "memory");
                STEPF(A8, 8, 16) STEPF(A9, 9, 16) STEPF(A10, 10, 16) STEPF(A11, 11, 16)
                STEPF(A12, 12, 16) STEPF(A13, 13, 16) STEPF(A14, 14, 16) STEPF(A15, 15, 16)
            } else {
                // kp=0: A = h0_t (hs0 slot s); kp=1: A = h1_{t-1} (hs1 slot s-1)
                const u16* arow = (kp == 0 ? hs0 + (size_t)s * 65536
                                           : hs1 + (size_t)(s - 1) * 65536)
                                + (size_t)(rt * 16 + lm) * 1024 + lq * 8;
                const u16* bw0 = whs + kp * 32768 + lanoff;
                u32x4 A0 = ldg_c16(arow +   0), A1 = ldg_c16(arow +  32);
                u32x4 A2 = ldg_c16(arow +  64), A3 = ldg_c16(arow +  96);
                u32x4 A4 = ldg_c16(arow + 128), A5 = ldg_c16(arow + 160);
                u32x4 A6 = ldg_c16(arow + 192), A7 = ldg_c16(arow + 224);
                u32x4 A8 = ldg_c16(arow + 256), A9 = ldg_c16(arow + 288);
                u32x4 A10 = ldg_c16(arow + 320), A11 = ldg_c16(arow + 352);
                u32x4 A12 = ldg_c16(arow + 384), A13 = ldg_c16(arow + 416);
                u32x4 A14 = ldg_c16(arow + 448), A15 = ldg_c16(arow + 480);
                u32x4 A16 = ldg_c16(arow + 512), A17 = ldg_c16(arow + 544);
                u32x4 A18 = ldg_c16(arow + 576), A19 = ldg_c16(arow + 608);
                u32x4 A20 = ldg_c16(arow + 640), A21 = ldg_c16(arow + 672);
                u32x4 A22 = ldg_c16(arow + 704), A23 = ldg_c16(arow + 736);
                u32x4 A24 = ldg_c16(arow + 768), A25 = ldg_c16(arow + 800);
                u32x4 A26 = ldg_c16(arow + 832), A27 = ldg_c16(arow + 864);
                u32x4 A28 = ldg_c16(arow + 896), A29 = ldg_c16(arow + 928);
                u32x4 A30 = ldg_c16(arow + 960), A31 = ldg_c16(arow + 992);
                asm volatile("s_waitcnt vmcnt(24)"
                             : "+v"(A0), "+v"(A1), "+v"(A2), "+v"(A3),
                               "+v"(A4), "+v"(A5), "+v"(A6), "+v"(A7) :: "memory");
                STEPF(A0, 0, 32) STEPF(A1, 1, 32) STEPF(A2, 2, 32) STEPF(A3, 3, 32)
                STEPF(A4, 4, 32) STEPF(A5, 5, 32) STEPF(A6, 6, 32) STEPF(A7, 7, 32)
                asm volatile("s_waitcnt vmcnt(16)"
                             : "+v"(A8), "+v"(A9), "+v"(A10), "+v"(A11),
                               "+v"(A12), "+v"(A13), "+v"(A14), "+v"(A15) :: "memory");
                STEPF(A8, 8, 32) STEPF(A9, 9, 32) STEPF(A10, 10, 32) STEPF(A11, 11, 32)
                STEPF(A12, 12, 32) STEPF(A13, 13, 32) STEPF(A14, 14, 32) STEPF(A15, 15, 32)
                asm volatile("s_waitcnt vmcnt(8)"
                             : "+v"(A16), "+v"(A17), "+v"(A18), "+v"(A19),
                               "+v"(A20), "+v"(A21), "+v"(A22), "+v"(A23) :: "memory");
                STEPF(A16, 16, 32) STEPF(A17, 17, 32) STEPF(A18, 18, 32) STEPF(A19, 19, 32)
                STEPF(A20, 20, 32) STEPF(A21, 21, 32) STEPF(A22, 22, 32) STEPF(A23, 23, 32)
                asm volatile("s_waitcnt vmcnt(0)"
                             : "+v"(A24), "+v"(A25), "+v"(A26), "+v"(A27),
                               "+v"(A28), "+v"(A29), "+v"(A30), "+v"(A31) :: "memory");
                STEPF(A24, 24, 32) STEPF(A25, 25, 32) STEPF(A26, 26, 32) STEPF(A27, 27, 32)
                STEPF(A28, 28, 32) STEPF(A29, 29, 32) STEPF(A30, 30, 32) STEPF(A31, 31, 32)
            }
            #undef STEPF

            // z-tile -> LDS: row = rt*16 + lq*4 + r ; cols lm (grp0), 16+lm (grp1)
            {
                float* zb = zbuf + (size_t)kp * 2112;
                #pragma unroll
                for (int r = 0; r < 4; r++) {
                    int row = rt * 16 + lq * 4 + r;
                    zb[row * 33 + lm] = acc0[r];
                    zb[row * 33 + 16 + lm] = acc1[r];
                }
            }
            __syncthreads();

            // gates: thread (b,u); local col lc = gate*8+u
            {
                const float* z0 = zbuf + (size_t)b * 33;
                const float* z1 = z0 + 2112;
                float gi = z0[u]      + z1[u]      + (role ? bi0 : bf2f(zi0v));
                float gf = z0[8 + u]  + z1[8 + u]  + (role ? bi1 : bf2f(zi1v));
                float gg = z0[16 + u] + z1[16 + u] + (role ? bi2 : bf2f(zi2v));
                float go = z0[24 + u] + z1[24 + u] + (role ? bi3 : bf2f(zi3v));
                gi = fast_sigmoid(gi);
                gf = fast_sigmoid(gf);
                gg = fast_tanh(gg);
                go = fast_sigmoid(go);
                c = gf * c + gi * gg;
                float h = go * fast_tanh(c);
                unsigned hb = (unsigned)f2bf(h);
                unsigned other = __shfl_xor(hb, 1);
                if ((tid & 1) == 0) {
                    unsigned packed = hb | (other << 16);
                    unsigned* dst = (unsigned*)(hs_my + (size_t)(t + 1) * 65536
                                                + (size_t)b * 1024 + gcol);
                    __hip_atomic_store(dst, packed, __ATOMIC_RELAXED,
                                       __HIP_MEMORY_SCOPE_AGENT);
                }
                if (t == 127) {
                    c_out[(size_t)b * 1024 + gcol] = c;
                    h_out[(size_t)b * 1024 + gcol] = h;
                }
            }
            __syncthreads();   // zbuf reuse + vmcnt(0) drain: h stores at MALL
        }

        // ---- one-hop all-poll-all device barrier
        unsigned gen = (unsigned)(s + 1);
        if (tid == 0)
            __hip_atomic_store(&ctr[bk * 16], gen, __ATOMIC_RELAXED,
                               __HIP_MEMORY_SCOPE_AGENT);
        for (;;) {
            int ok = (tid >= FBLOCKS) ||
                     (__hip_atomic_load(&ctr[tid * 16], __ATOMIC_RELAXED,
                                        __HIP_MEMORY_SCOPE_AGENT) >= gen);
            if (__syncthreads_count(ok) == 512) break;
        }
    }
}

// ---------------- logits: [8192,1024]bf16 @ WoT[32,1024]bf16 + b_out -> f32 ----------------
// A rows are t*64+b ; output index (b*128+t)*32+n
__global__ __launch_bounds__(256) void k_logits(const u16* __restrict__ Pact,
                                                const u16* __restrict__ WoT,
                                                const float* __restrict__ bout,
                                                float* __restrict__ out) {
    int r = blockIdx.x * 8 + (threadIdx.x >> 5);
    int n = threadIdx.x & 31;
    const u16* a = Pact + (size_t)r * 1024;
    const u16* wv = WoT + (size_t)n * 1024;
    float s = 0.f;
    for (int k = 0; k < 1024; k += 8) {
        short8 av = *(const short8*)(a + k);
        short8 wvv = *(const short8*)(wv + k);
        #pragma unroll
        for (int j = 0; j < 8; j++)
            s += bf2f((u16)av[j]) * bf2f((u16)wvv[j]);
    }
    int t = r >> 6, b = r & 63;
    out[((size_t)b * 128 + t) * 32 + n] = s + bout[n];
}

// ---------------- launcher ----------------
extern "C" void kernel_launch(void* const* d_in, const int* in_sizes, int n_in,
                              void* d_out, int out_size, void* d_ws, size_t ws_size,
                              hipStream_t stream) {
    const float* x      = (const float*)d_in[0];
    const float* c0     = (const float*)d_in[1];
    const float* h0     = (const float*)d_in[2];
    const float* W_pre  = (const float*)d_in[3];
    const float* b_pre  = (const float*)d_in[4];
    const float* ln_s   = (const float*)d_in[5];
    const float* ln_b   = (const float*)d_in[6];
    const float* Wi0    = (const float*)d_in[7];
    const float* Wh0    = (const float*)d_in[8];
    const float* b0     = (const float*)d_in[9];
    const float* Wi1    = (const float*)d_in[10];
    const float* Wh1    = (const float*)d_in[11];
    const float* b1     = (const float*)d_in[12];
    const float* W_post = (const float*)d_in[13];
    const float* b_post = (const float*)d_in[14];
    const float* W_out  = (const float*)d_in[15];
    const float* b_out  = (const float*)d_in[16];
    float* out = (float*)d_out;

    char* ws = (char*)d_ws;
    size_t off = 0;
    auto alloc = [&](size_t bytes) {
        void* p = ws + off;
        off += (bytes + 255) & ~(size_t)255;
        return p;
    };
    u16* WTpre  = (u16*)alloc((size_t)1024 * 512 * 2);
    u16* WTi0   = (u16*)alloc((size_t)4096 * 1024 * 2);
    u16* WTh0   = (u16*)alloc((size_t)4096 * 1024 * 2);
    u16* WTi1   = (u16*)alloc((size_t)4096 * 1024 * 2);
    u16* WTh1   = (u16*)alloc((size_t)4096 * 1024 * 2);
    u16* WTpost = (u16*)alloc((size_t)1024 * 1024 * 2);
    u16* WTout  = (u16*)alloc((size_t)32 * 1024 * 2);
    u16* Xb     = (u16*)alloc((size_t)8192 * 512 * 2);
    u16* preact = (u16*)alloc((size_t)8192 * 1024 * 2);
    u16* hs0    = (u16*)alloc((size_t)129 * 65536 * 2);
    u16* hs1    = (u16*)alloc((size_t)129 * 65536 * 2);
    u16* postact= (u16*)alloc((size_t)8192 * 1024 * 2);
    unsigned* ctr = (unsigned*)alloc(32768);
    void* unionreg = alloc((size_t)8192 * 4096 * 2); // Zi0 bf16 (64MB) / pre_f32 (32MB)
    float* pre_f32 = (float*)unionreg;
    u16* Zi = (u16*)unionreg;

    // init: counters + bf16 conversions
    k_zero<<<32, 256, 0, stream>>>(ctr, 8192);
    k_cvt<<<(8192 * 512) / 256, 256, 0, stream>>>(x, Xb, 8192 * 512);
    k_cvt<<<256, 256, 0, stream>>>(h0, hs0, 65536);
    k_cvt<<<256, 256, 0, stream>>>(h0 + 65536, hs1, 65536);

    // weight transpose+convert
    k_transpose<<<dim3(32, 16), 256, 0, stream>>>(W_pre, WTpre, 512, 1024);
    k_transpose<<<dim3(128, 32), 256, 0, stream>>>(Wi0, WTi0, 1024, 4096);
    k_transpose<<<dim3(128, 32), 256, 0, stream>>>(Wh0, WTh0, 1024, 4096);
    k_transpose<<<dim3(128, 32), 256, 0, stream>>>(Wi1, WTi1, 1024, 4096);
    k_transpose<<<dim3(128, 32), 256, 0, stream>>>(Wh1, WTh1, 1024, 4096);
    k_transpose<<<dim3(32, 32), 256, 0, stream>>>(W_post, WTpost, 1024, 1024);
    k_transpose<<<dim3(1, 32), 256, 0, stream>>>(W_out, WTout, 1024, 32);

    // pre: Dense + LN + relu
    k_gemm<0><<<dim3(16, 128), 256, 0, stream>>>(Xb, WTpre, b_pre, pre_f32, 8192, 1024, 512);
    k_ln_relu<<<8192, 256, 0, stream>>>(pre_f32, ln_s, ln_b, preact);

    // Zi0 = preact @ Wi0 + b0  (row = b*128 + t)
    k_gemm<1><<<dim3(64, 128), 256, 0, stream>>>(preact, WTi0, b0, Zi, 8192, 4096, 1024);

    // fused 2-layer pipelined scan
    {
        const u16* WhT0_ = WTh0; const u16* WiT1_ = WTi1; const u16* WhT1_ = WTh1;
        const u16* Zi_ = Zi; const float* b1_ = b1; const float* c0_ = c0;
        u16* hs0_ = hs0; u16* hs1_ = hs1; float* out_ = out; unsigned* ctr_ = ctr;
        void* args[] = {&WhT0_, &WiT1_, &WhT1_, &Zi_, &b1_, &c0_,
                        &hs0_, &hs1_, &out_, &ctr_};
        hipLaunchCooperativeKernel((void*)k_lstm_fused, dim3(FBLOCKS), dim3(512),
                                   args, 0, stream);
    }

    // post Dense+relu, then logits
    k_gemm<2><<<dim3(16, 128), 256, 0, stream>>>(hs1 + 65536, WTpost, b_post, postact,
                                                 8192, 1024, 1024);
    k_logits<<<1024, 256, 0, stream>>>(postact, WTout, b_out, out + 262144);
}

// Round 5
// 2303.800 us; speedup vs baseline: 4.1481x; 1.0158x over previous
//
#include <hip/hip_runtime.h>
#include <hip/hip_bf16.h>
#include <math.h>

typedef __attribute__((ext_vector_type(8))) short short8;
typedef __attribute__((ext_vector_type(4))) float f32x4;
typedef __attribute__((ext_vector_type(4))) unsigned u32x4;
typedef unsigned short u16;
typedef unsigned long long u64;

__device__ __forceinline__ u16 f2bf(float f) {
    union { float f; unsigned u; } v; v.f = f;
    unsigned r = v.u + 0x7fffu + ((v.u >> 16) & 1u);   // RNE
    return (u16)(r >> 16);
}
__device__ __forceinline__ float bf2f(u16 b) {
    union { unsigned u; float f; } v; v.u = ((unsigned)b) << 16;
    return v.f;
}
__device__ __forceinline__ float fast_sigmoid(float x) {
    return __builtin_amdgcn_rcpf(1.f + __expf(-x));
}
__device__ __forceinline__ float fast_tanh(float x) {
    return 1.f - 2.f * __builtin_amdgcn_rcpf(1.f + __expf(2.f * x));
}
// cached (L1/L2) pipelined 16-B load; asm so it can't be hoisted above spins
__device__ __forceinline__ u32x4 ldg16(const void* p) {
    u32x4 r;
    asm volatile("global_load_dwordx4 %0, %1, off"
                 : "=v"(r) : "v"(p) : "memory");
    return r;
}

// ---------------- utility kernels ----------------

__global__ __launch_bounds__(256) void k_zero(unsigned* p, int n) {
    int i = blockIdx.x * 256 + threadIdx.x;
    if (i < n) p[i] = 0u;
}

__global__ __launch_bounds__(256) void k_cvt(const float* __restrict__ in,
                                             u16* __restrict__ out, int n) {
    int i = blockIdx.x * 256 + threadIdx.x;
    if (i < n) out[i] = f2bf(in[i]);
}

// W[K][N] f32 -> WT[N][K] bf16
__global__ __launch_bounds__(256) void k_transpose(const float* __restrict__ W,
                                                   u16* __restrict__ WT, int K, int N) {
    __shared__ float tile[32][33];
    int n0 = blockIdx.x * 32, k0 = blockIdx.y * 32;
    int tx = threadIdx.x & 31, ty = threadIdx.x >> 5;
    #pragma unroll
    for (int j = 0; j < 32; j += 8)
        tile[ty + j][tx] = W[(size_t)(k0 + ty + j) * N + n0 + tx];
    __syncthreads();
    #pragma unroll
    for (int j = 0; j < 32; j += 8)
        WT[(size_t)(n0 + ty + j) * K + k0 + tx] = f2bf(tile[tx][ty + j]);
}

// ---------------- generic bf16 MFMA GEMM ----------------
// C[M,N] = A[M,K] * BT[N,K]^T + bias ; MODE 0: f32 out, 1: bf16 out, 2: bf16 relu out
template <int MODE>
__global__ __launch_bounds__(256) void k_gemm(const u16* __restrict__ A,
                                              const u16* __restrict__ BT,
                                              const float* __restrict__ bias,
                                              void* __restrict__ Cout,
                                              int M, int N, int K) {
    const int w = threadIdx.x >> 6, l = threadIdx.x & 63;
    const int lm = l & 15, lq = l >> 4;
    const int r0 = blockIdx.y * 64 + w * 16;
    const int c0 = blockIdx.x * 64;
    const u16* arow = A + (size_t)(r0 + lm) * K + lq * 8;
    const u16* bp0 = BT + (size_t)(c0 + lm) * K + lq * 8;
    const u16* bp1 = bp0 + (size_t)16 * K;
    const u16* bp2 = bp0 + (size_t)32 * K;
    const u16* bp3 = bp0 + (size_t)48 * K;
    f32x4 acc0 = {0.f, 0.f, 0.f, 0.f}, acc1 = acc0, acc2 = acc0, acc3 = acc0;
    for (int k0 = 0; k0 < K; k0 += 32) {
        short8 a = *(const short8*)(arow + k0);
        acc0 = __builtin_amdgcn_mfma_f32_16x16x32_bf16(a, *(const short8*)(bp0 + k0), acc0, 0, 0, 0);
        acc1 = __builtin_amdgcn_mfma_f32_16x16x32_bf16(a, *(const short8*)(bp1 + k0), acc1, 0, 0, 0);
        acc2 = __builtin_amdgcn_mfma_f32_16x16x32_bf16(a, *(const short8*)(bp2 + k0), acc2, 0, 0, 0);
        acc3 = __builtin_amdgcn_mfma_f32_16x16x32_bf16(a, *(const short8*)(bp3 + k0), acc3, 0, 0, 0);
    }
    f32x4 accs[4] = {acc0, acc1, acc2, acc3};
    #pragma unroll
    for (int nt = 0; nt < 4; nt++) {
        #pragma unroll
        for (int r = 0; r < 4; r++) {
            int row = r0 + lq * 4 + r;          // C/D layout: row=(l>>4)*4+reg
            int col = c0 + nt * 16 + lm;        //             col=l&15
            float v = accs[nt][r] + bias[col];
            if (MODE == 0) {
                ((float*)Cout)[(size_t)row * N + col] = v;
            } else {
                if (MODE == 2) v = fmaxf(v, 0.f);
                ((u16*)Cout)[(size_t)row * N + col] = f2bf(v);
            }
        }
    }
}

// ---------------- LayerNorm + ReLU (row width 1024) ----------------
__global__ __launch_bounds__(256) void k_ln_relu(const float* __restrict__ X,
                                                 const float* __restrict__ scale,
                                                 const float* __restrict__ bias,
                                                 u16* __restrict__ Y) {
    const int N = 1024;
    size_t row = blockIdx.x;
    const float* x = X + row * N;
    float s = 0.f, ss = 0.f;
    float vals[4];
    #pragma unroll
    for (int j = 0; j < 4; j++) {
        float v = x[threadIdx.x + 256 * j];
        vals[j] = v; s += v; ss += v * v;
    }
    #pragma unroll
    for (int o = 32; o > 0; o >>= 1) { s += __shfl_down(s, o); ss += __shfl_down(ss, o); }
    __shared__ float rs[4], rss[4];
    int w = threadIdx.x >> 6;
    if ((threadIdx.x & 63) == 0) { rs[w] = s; rss[w] = ss; }
    __syncthreads();
    __shared__ float smu, sinv;
    if (threadIdx.x == 0) {
        float a = rs[0] + rs[1] + rs[2] + rs[3];
        float bq = rss[0] + rss[1] + rss[2] + rss[3];
        float mu = a * (1.f / N);
        float var = bq * (1.f / N) - mu * mu;
        smu = mu; sinv = rsqrtf(var + 1e-6f);
    }
    __syncthreads();
    float mu = smu, inv = sinv;
    #pragma unroll
    for (int j = 0; j < 4; j++) {
        int i = threadIdx.x + 256 * j;
        float v = (vals[j] - mu) * inv * scale[i] + bias[i];
        Y[row * N + i] = f2bf(fmaxf(v, 0.f));
    }
}

// ---------------- fused 2-layer persistent LSTM scan ----------------
// 256 blocks x 512 threads, 1 block/CU. Blocks 0..127 = layer 0 (step t),
// blocks 128..255 = layer 1 (step t, lagging layer 0 by one publish).
// DECOUPLED sync: layer 0 waits only on layer-0 arrivals (ctr[0..127] >= t);
// layer 1 waits on ctr0 >= t+1 (h0_t ready) and ctr1 >= t (own h1_{t-1}).
// Layer 0 never waits on layer 1 (fresh slot addresses -> no WAR hazard).
// h stores: sc0/sc1 write-through to MALL, drained by __syncthreads before
// publish. h loads: PLAIN CACHED — safe because a slot line is only ever
// read after all its producers published (no CU/L2 can hold a stale copy;
// dispatch-start acquire invalidates caches from previous launches), and the
// XCD L2 then serves the 32-block broadcast (MALL traffic /24).
// B (weights) in MFMA-fragment order in LDS: lane-linear conflict-free reads.
#define FBLOCKS 256
__global__ __launch_bounds__(512, 1) void k_lstm_fused(
    const u16* __restrict__ WhT0, const u16* __restrict__ WiT1,
    const u16* __restrict__ WhT1, const u16* __restrict__ Zi0,
    const float* __restrict__ b1v, const float* __restrict__ c0_all,
    u16* __restrict__ hs0, u16* __restrict__ hs1,
    float* __restrict__ out, unsigned* __restrict__ ctr) {
    const int bk = blockIdx.x;
    const int role = bk >> 7;          // 0: layer0, 1: layer1
    const int bkl = bk & 127;
    const int tid = threadIdx.x;
    const int w = tid >> 6, l = tid & 63, lm = l & 15, lq = l >> 4;
    const int kp = w >> 2, rt = w & 3;

    __shared__ u16 whs[65536];          // 128 KB fragment-ordered B
    __shared__ float zbuf[2 * 64 * 33]; // [kp][batch][32 cols]

    // ---- stage B slices in fragment order (linear: dst = whs + f*8)
    {
        const int NI = role ? 32 : 16;
        const int F = role ? 8192 : 4096;
        const int ISH = role ? 5 : 4;
        for (int f = tid; f < F; f += 512) {
            int flm = f & 15, flq = (f >> 4) & 3;
            int fi = (f >> 6) & (NI - 1);
            int rest = f >> (6 + ISH);
            int fg = rest & 1, fkp = (rest >> 1) & 1;
            int lc = fg * 16 + flm;
            int gcolw = (lc >> 3) * 1024 + bkl * 8 + (lc & 7);
            int k = fi * 32 + flq * 8;
            const u16* src = role
                ? ((fkp == 0 ? WiT1 : WhT1) + (size_t)gcolw * 1024 + k)
                : (WhT0 + (size_t)gcolw * 1024 + fkp * 512 + k);
            *(short8*)(whs + (size_t)f * 8) = *(const short8*)src;
        }
    }
    const int u = tid & 7, b = tid >> 3;
    const int gcol = bkl * 8 + u;
    float c = (c0_all + (size_t)role * 65536)[(size_t)b * 1024 + gcol];
    float bi0 = 0.f, bi1 = 0.f, bi2 = 0.f, bi3 = 0.f;
    if (role) {
        bi0 = b1v[gcol]; bi1 = b1v[1024 + gcol];
        bi2 = b1v[2048 + gcol]; bi3 = b1v[3072 + gcol];
    }
    u16* hs_my = role ? hs1 : hs0;
    float* c_out = out + (size_t)role * 65536;
    float* h_out = out + 131072 + (size_t)role * 65536;
    const int lanoff = (lq * 16 + lm) * 8;
    __syncthreads();

    for (int t = 0; t < 128; t++) {
        // ---- wait for dependencies (role-specific, decoupled)
        if (!role) {
            if (t > 0) {
                for (;;) {
                    int ok = (tid >= 128) ||
                             (__hip_atomic_load(&ctr[tid * 16], __ATOMIC_RELAXED,
                                                __HIP_MEMORY_SCOPE_AGENT) >= (unsigned)t);
                    if (__syncthreads_count(ok) == 512) break;
                }
            }
        } else {
            unsigned need = (tid < 128) ? (unsigned)(t + 1) : (unsigned)t;
            for (;;) {
                int ok = (tid >= 256) ||
                         (__hip_atomic_load(&ctr[tid * 16], __ATOMIC_RELAXED,
                                            __HIP_MEMORY_SCOPE_AGENT) >= need);
                if (__syncthreads_count(ok) == 512) break;
            }
        }

        u16 zi0v = 0, zi1v = 0, zi2v = 0, zi3v = 0;
        f32x4 acc0 = {0.f, 0.f, 0.f, 0.f}, acc1 = acc0;

        #define STEPF(Ai, i, NI)                                                  \
        {   union { u32x4 q; short8 v; } _a; _a.q = (Ai);                         \
            short8 _b0 = *(const short8*)(bw0 + (i) * 512);                       \
            short8 _b1 = *(const short8*)(bw0 + (NI) * 512 + (i) * 512);          \
            acc0 = __builtin_amdgcn_mfma_f32_16x16x32_bf16(_a.v, _b0, acc0, 0, 0, 0); \
            acc1 = __builtin_amdgcn_mfma_f32_16x16x32_bf16(_a.v, _b1, acc1, 0, 0, 0); }

        if (!role) {
            // Zi prefetch (plain cached loads, in flight during A loads)
            const u16* zi = Zi0 + ((size_t)b * 128 + t) * 4096 + gcol;
            zi0v = zi[0]; zi1v = zi[1024]; zi2v = zi[2048]; zi3v = zi[3072];
            const u16* arow = hs0 + (size_t)t * 65536
                            + (size_t)(rt * 16 + lm) * 1024 + kp * 512 + lq * 8;
            const u16* bw0 = whs + kp * 16384 + lanoff;
            u32x4 A0 = ldg16(arow +   0), A1 = ldg16(arow +  32);
            u32x4 A2 = ldg16(arow +  64), A3 = ldg16(arow +  96);
            u32x4 A4 = ldg16(arow + 128), A5 = ldg16(arow + 160);
            u32x4 A6 = ldg16(arow + 192), A7 = ldg16(arow + 224);
            u32x4 A8 = ldg16(arow + 256), A9 = ldg16(arow + 288);
            u32x4 A10 = ldg16(arow + 320), A11 = ldg16(arow + 352);
            u32x4 A12 = ldg16(arow + 384), A13 = ldg16(arow + 416);
            u32x4 A14 = ldg16(arow + 448), A15 = ldg16(arow + 480);
            asm volatile("s_waitcnt vmcnt(8)"
                         : "+v"(A0), "+v"(A1), "+v"(A2), "+v"(A3),
                           "+v"(A4), "+v"(A5), "+v"(A6), "+v"(A7) :: "memory");
            STEPF(A0, 0, 16) STEPF(A1, 1, 16) STEPF(A2, 2, 16) STEPF(A3, 3, 16)
            STEPF(A4, 4, 16) STEPF(A5, 5, 16) STEPF(A6, 6, 16) STEPF(A7, 7, 16)
            asm volatile("s_waitcnt vmcnt(0)"
                         : "+v"(A8), "+v"(A9), "+v"(A10), "+v"(A11),
                           "+v"(A12), "+v"(A13), "+v"(A14), "+v"(A15) :: "memory");
            STEPF(A8, 8, 16) STEPF(A9, 9, 16) STEPF(A10, 10, 16) STEPF(A11, 11, 16)
            STEPF(A12, 12, 16) STEPF(A13, 13, 16) STEPF(A14, 14, 16) STEPF(A15, 15, 16)
        } else {
            // kp=0: A = h0_t (hs0 slot t+1); kp=1: A = h1_{t-1} (hs1 slot t)
            const u16* arow = (kp == 0 ? hs0 + (size_t)(t + 1) * 65536
                                       : hs1 + (size_t)t * 65536)
                            + (size_t)(rt * 16 + lm) * 1024 + lq * 8;
            const u16* bw0 = whs + kp * 32768 + lanoff;
            u32x4 A0 = ldg16(arow +   0), A1 = ldg16(arow +  32);
            u32x4 A2 = ldg16(arow +  64), A3 = ldg16(arow +  96);
            u32x4 A4 = ldg16(arow + 128), A5 = ldg16(arow + 160);
            u32x4 A6 = ldg16(arow + 192), A7 = ldg16(arow + 224);
            u32x4 A8 = ldg16(arow + 256), A9 = ldg16(arow + 288);
            u32x4 A10 = ldg16(arow + 320), A11 = ldg16(arow + 352);
            u32x4 A12 = ldg16(arow + 384), A13 = ldg16(arow + 416);
            u32x4 A14 = ldg16(arow + 448), A15 = ldg16(arow + 480);
            u32x4 A16 = ldg16(arow + 512), A17 = ldg16(arow + 544);
            u32x4 A18 = ldg16(arow + 576), A19 = ldg16(arow + 608);
            u32x4 A20 = ldg16(arow + 640), A21 = ldg16(arow + 672);
            u32x4 A22 = ldg16(arow + 704), A23 = ldg16(arow + 736);
            u32x4 A24 = ldg16(arow + 768), A25 = ldg16(arow + 800);
            u32x4 A26 = ldg16(arow + 832), A27 = ldg16(arow + 864);
            u32x4 A28 = ldg16(arow + 896), A29 = ldg16(arow + 928);
            u32x4 A30 = ldg16(arow + 960), A31 = ldg16(arow + 992);
            asm volatile("s_waitcnt vmcnt(24)"
                         : "+v"(A0), "+v"(A1), "+v"(A2), "+v"(A3),
                           "+v"(A4), "+v"(A5), "+v"(A6), "+v"(A7) :: "memory");
            STEPF(A0, 0, 32) STEPF(A1, 1, 32) STEPF(A2, 2, 32) STEPF(A3, 3, 32)
            STEPF(A4, 4, 32) STEPF(A5, 5, 32) STEPF(A6, 6, 32) STEPF(A7, 7, 32)
            asm volatile("s_waitcnt vmcnt(16)"
                         : "+v"(A8), "+v"(A9), "+v"(A10), "+v"(A11),
                           "+v"(A12), "+v"(A13), "+v"(A14), "+v"(A15) :: "memory");
            STEPF(A8, 8, 32) STEPF(A9, 9, 32) STEPF(A10, 10, 32) STEPF(A11, 11, 32)
            STEPF(A12, 12, 32) STEPF(A13, 13, 32) STEPF(A14, 14, 32) STEPF(A15, 15, 32)
            asm volatile("s_waitcnt vmcnt(8)"
                         : "+v"(A16), "+v"(A17), "+v"(A18), "+v"(A19),
                           "+v"(A20), "+v"(A21), "+v"(A22), "+v"(A23) :: "memory");
            STEPF(A16, 16, 32) STEPF(A17, 17, 32) STEPF(A18, 18, 32) STEPF(A19, 19, 32)
            STEPF(A20, 20, 32) STEPF(A21, 21, 32) STEPF(A22, 22, 32) STEPF(A23, 23, 32)
            asm volatile("s_waitcnt vmcnt(0)"
                         : "+v"(A24), "+v"(A25), "+v"(A26), "+v"(A27),
                           "+v"(A28), "+v"(A29), "+v"(A30), "+v"(A31) :: "memory");
            STEPF(A24, 24, 32) STEPF(A25, 25, 32) STEPF(A26, 26, 32) STEPF(A27, 27, 32)
            STEPF(A28, 28, 32) STEPF(A29, 29, 32) STEPF(A30, 30, 32) STEPF(A31, 31, 32)
        }
        #undef STEPF

        // z-tile -> LDS: row = rt*16 + lq*4 + r ; cols lm (grp0), 16+lm (grp1)
        {
            float* zb = zbuf + (size_t)kp * 2112;
            #pragma unroll
            for (int r = 0; r < 4; r++) {
                int row = rt * 16 + lq * 4 + r;
                zb[row * 33 + lm] = acc0[r];
                zb[row * 33 + 16 + lm] = acc1[r];
            }
        }
        __syncthreads();

        // gates: thread (b,u); local col lc = gate*8+u
        {
            const float* z0 = zbuf + (size_t)b * 33;
            const float* z1 = z0 + 2112;
            float gi = z0[u]      + z1[u]      + (role ? bi0 : bf2f(zi0v));
            float gf = z0[8 + u]  + z1[8 + u]  + (role ? bi1 : bf2f(zi1v));
            float gg = z0[16 + u] + z1[16 + u] + (role ? bi2 : bf2f(zi2v));
            float go = z0[24 + u] + z1[24 + u] + (role ? bi3 : bf2f(zi3v));
            gi = fast_sigmoid(gi);
            gf = fast_sigmoid(gf);
            gg = fast_tanh(gg);
            go = fast_sigmoid(go);
            c = gf * c + gi * gg;
            float h = go * fast_tanh(c);
            unsigned hb = (unsigned)f2bf(h);
            unsigned other = __shfl_xor(hb, 1);
            if ((tid & 1) == 0) {
                unsigned packed = hb | (other << 16);
                unsigned* dst = (unsigned*)(hs_my + (size_t)(t + 1) * 65536
                                            + (size_t)b * 1024 + gcol);
                __hip_atomic_store(dst, packed, __ATOMIC_RELAXED,
                                   __HIP_MEMORY_SCOPE_AGENT);
            }
            if (t == 127) {
                c_out[(size_t)b * 1024 + gcol] = c;
                h_out[(size_t)b * 1024 + gcol] = h;
            }
        }
        __syncthreads();   // zbuf reuse + vmcnt(0) drain: h stores at MALL

        // ---- publish arrival (slot per block, 64 B apart)
        if (tid == 0)
            __hip_atomic_store(&ctr[bk * 16], (unsigned)(t + 1), __ATOMIC_RELAXED,
                               __HIP_MEMORY_SCOPE_AGENT);
    }
}

// ---------------- logits: [8192,1024]bf16 @ WoT[32,1024]bf16 + b_out -> f32 ----------------
// A rows are t*64+b ; output index (b*128+t)*32+n
__global__ __launch_bounds__(256) void k_logits(const u16* __restrict__ Pact,
                                                const u16* __restrict__ WoT,
                                                const float* __restrict__ bout,
                                                float* __restrict__ out) {
    int r = blockIdx.x * 8 + (threadIdx.x >> 5);
    int n = threadIdx.x & 31;
    const u16* a = Pact + (size_t)r * 1024;
    const u16* wv = WoT + (size_t)n * 1024;
    float s = 0.f;
    for (int k = 0; k < 1024; k += 8) {
        short8 av = *(const short8*)(a + k);
        short8 wvv = *(const short8*)(wv + k);
        #pragma unroll
        for (int j = 0; j < 8; j++)
            s += bf2f((u16)av[j]) * bf2f((u16)wvv[j]);
    }
    int t = r >> 6, b = r & 63;
    out[((size_t)b * 128 + t) * 32 + n] = s + bout[n];
}

// ---------------- launcher ----------------
extern "C" void kernel_launch(void* const* d_in, const int* in_sizes, int n_in,
                              void* d_out, int out_size, void* d_ws, size_t ws_size,
                              hipStream_t stream) {
    const float* x      = (const float*)d_in[0];
    const float* c0     = (const float*)d_in[1];
    const float* h0     = (const float*)d_in[2];
    const float* W_pre  = (const float*)d_in[3];
    const float* b_pre  = (const float*)d_in[4];
    const float* ln_s   = (const float*)d_in[5];
    const float* ln_b   = (const float*)d_in[6];
    const float* Wi0    = (const float*)d_in[7];
    const float* Wh0    = (const float*)d_in[8];
    const float* b0     = (const float*)d_in[9];
    const float* Wi1    = (const float*)d_in[10];
    const float* Wh1    = (const float*)d_in[11];
    const float* b1     = (const float*)d_in[12];
    const float* W_post = (const float*)d_in[13];
    const float* b_post = (const float*)d_in[14];
    const float* W_out  = (const float*)d_in[15];
    const float* b_out  = (const float*)d_in[16];
    float* out = (float*)d_out;

    char* ws = (char*)d_ws;
    size_t off = 0;
    auto alloc = [&](size_t bytes) {
        void* p = ws + off;
        off += (bytes + 255) & ~(size_t)255;
        return p;
    };
    u16* WTpre  = (u16*)alloc((size_t)1024 * 512 * 2);
    u16* WTi0   = (u16*)alloc((size_t)4096 * 1024 * 2);
    u16* WTh0   = (u16*)alloc((size_t)4096 * 1024 * 2);
    u16* WTi1   = (u16*)alloc((size_t)4096 * 1024 * 2);
    u16* WTh1   = (u16*)alloc((size_t)4096 * 1024 * 2);
    u16* WTpost = (u16*)alloc((size_t)1024 * 1024 * 2);
    u16* WTout  = (u16*)alloc((size_t)32 * 1024 * 2);
    u16* Xb     = (u16*)alloc((size_t)8192 * 512 * 2);
    u16* preact = (u16*)alloc((size_t)8192 * 1024 * 2);
    u16* hs0    = (u16*)alloc((size_t)129 * 65536 * 2);
    u16* hs1    = (u16*)alloc((size_t)129 * 65536 * 2);
    u16* postact= (u16*)alloc((size_t)8192 * 1024 * 2);
    unsigned* ctr = (unsigned*)alloc(32768);
    void* unionreg = alloc((size_t)8192 * 4096 * 2); // Zi0 bf16 (64MB) / pre_f32 (32MB)
    float* pre_f32 = (float*)unionreg;
    u16* Zi = (u16*)unionreg;

    // init: counters + bf16 conversions
    k_zero<<<32, 256, 0, stream>>>(ctr, 8192);
    k_cvt<<<(8192 * 512) / 256, 256, 0, stream>>>(x, Xb, 8192 * 512);
    k_cvt<<<256, 256, 0, stream>>>(h0, hs0, 65536);
    k_cvt<<<256, 256, 0, stream>>>(h0 + 65536, hs1, 65536);

    // weight transpose+convert
    k_transpose<<<dim3(32, 16), 256, 0, stream>>>(W_pre, WTpre, 512, 1024);
    k_transpose<<<dim3(128, 32), 256, 0, stream>>>(Wi0, WTi0, 1024, 4096);
    k_transpose<<<dim3(128, 32), 256, 0, stream>>>(Wh0, WTh0, 1024, 4096);
    k_transpose<<<dim3(128, 32), 256, 0, stream>>>(Wi1, WTi1, 1024, 4096);
    k_transpose<<<dim3(128, 32), 256, 0, stream>>>(Wh1, WTh1, 1024, 4096);
    k_transpose<<<dim3(32, 32), 256, 0, stream>>>(W_post, WTpost, 1024, 1024);
    k_transpose<<<dim3(1, 32), 256, 0, stream>>>(W_out, WTout, 1024, 32);

    // pre: Dense + LN + relu
    k_gemm<0><<<dim3(16, 128), 256, 0, stream>>>(Xb, WTpre, b_pre, pre_f32, 8192, 1024, 512);
    k_ln_relu<<<8192, 256, 0, stream>>>(pre_f32, ln_s, ln_b, preact);

    // Zi0 = preact @ Wi0 + b0  (row = b*128 + t)
    k_gemm<1><<<dim3(64, 128), 256, 0, stream>>>(preact, WTi0, b0, Zi, 8192, 4096, 1024);

    // fused 2-layer pipelined scan
    {
        const u16* WhT0_ = WTh0; const u16* WiT1_ = WTi1; const u16* WhT1_ = WTh1;
        const u16* Zi_ = Zi; const float* b1_ = b1; const float* c0_ = c0;
        u16* hs0_ = hs0; u16* hs1_ = hs1; float* out_ = out; unsigned* ctr_ = ctr;
        void* args[] = {&WhT0_, &WiT1_, &WhT1_, &Zi_, &b1_, &c0_,
                        &hs0_, &hs1_, &out_, &ctr_};
        hipLaunchCooperativeKernel((void*)k_lstm_fused, dim3(FBLOCKS), dim3(512),
                                   args, 0, stream);
    }

    // post Dense+relu, then logits
    k_gemm<2><<<dim3(16, 128), 256, 0, stream>>>(hs1 + 65536, WTpost, b_post, postact,
                                                 8192, 1024, 1024);
    k_logits<<<1024, 256, 0, stream>>>(postact, WTout, b_out, out + 262144);
}

// Round 7
// 1758.681 us; speedup vs baseline: 5.4338x; 1.3100x over previous
//
#include <hip/hip_runtime.h>
#include <hip/hip_bf16.h>
#include <math.h>

typedef __attribute__((ext_vector_type(8))) short short8;
typedef __attribute__((ext_vector_type(4))) float f32x4;
typedef __attribute__((ext_vector_type(4))) unsigned u32x4;
typedef unsigned short u16;
typedef unsigned long long u64;

__device__ __forceinline__ u16 f2bf(float f) {
    union { float f; unsigned u; } v; v.f = f;
    unsigned r = v.u + 0x7fffu + ((v.u >> 16) & 1u);   // RNE
    return (u16)(r >> 16);
}
__device__ __forceinline__ float bf2f(u16 b) {
    union { unsigned u; float f; } v; v.u = ((unsigned)b) << 16;
    return v.f;
}
__device__ __forceinline__ float fast_sigmoid(float x) {
    return __builtin_amdgcn_rcpf(1.f + __expf(-x));
}
__device__ __forceinline__ float fast_tanh(float x) {
    return 1.f - 2.f * __builtin_amdgcn_rcpf(1.f + __expf(2.f * x));
}
// cached (L1/L2) pipelined 16-B load; asm so it can't be hoisted above spins.
// NOTE: constraint MUST be "=v" (VGPR) — "=r" allows SGPR dest, which is
// invalid for VMEM loads (round-6 compile failure).
__device__ __forceinline__ u32x4 ldg16(const void* p) {
    u32x4 r;
    asm volatile("global_load_dwordx4 %0, %1, off"
                 : "=v"(r) : "v"(p) : "memory");
    return r;
}

// ---------------- utility kernels ----------------

__global__ __launch_bounds__(256) void k_zero(unsigned* p, int n) {
    int i = blockIdx.x * 256 + threadIdx.x;
    if (i < n) p[i] = 0u;
}

__global__ __launch_bounds__(256) void k_cvt(const float* __restrict__ in,
                                             u16* __restrict__ out, int n) {
    int i = blockIdx.x * 256 + threadIdx.x;
    if (i < n) out[i] = f2bf(in[i]);
}

// h0 [B=64][H=1024] f32 -> hs slot-0 layout [g=j>>3][b][j&7] bf16
__global__ __launch_bounds__(256) void k_cvt_h(const float* __restrict__ in,
                                               u16* __restrict__ out) {
    int i = blockIdx.x * 256 + threadIdx.x;   // 65536 threads
    int b = i >> 10, j = i & 1023;
    out[(size_t)(j >> 3) * 512 + b * 8 + (j & 7)] = f2bf(in[i]);
}

// hs1 slots 1..128 [t][g][b][8] -> plain [row=t*64+b][1024]
__global__ __launch_bounds__(256) void k_repack(const u16* __restrict__ hs1,
                                                u16* __restrict__ Hp) {
    int n = blockIdx.x * 256 + threadIdx.x;   // 1M transfers, 16B each
    int row = n >> 7, g = n & 127;
    int t = row >> 6, b = row & 63;
    const u16* src = hs1 + (size_t)(t + 1) * 65536 + (size_t)g * 512 + b * 8;
    u16* dst = Hp + (size_t)row * 1024 + g * 8;
    *(u32x4*)dst = *(const u32x4*)src;
}

// W[K][N] f32 -> WT[N][K] bf16
__global__ __launch_bounds__(256) void k_transpose(const float* __restrict__ W,
                                                   u16* __restrict__ WT, int K, int N) {
    __shared__ float tile[32][33];
    int n0 = blockIdx.x * 32, k0 = blockIdx.y * 32;
    int tx = threadIdx.x & 31, ty = threadIdx.x >> 5;
    #pragma unroll
    for (int j = 0; j < 32; j += 8)
        tile[ty + j][tx] = W[(size_t)(k0 + ty + j) * N + n0 + tx];
    __syncthreads();
    #pragma unroll
    for (int j = 0; j < 32; j += 8)
        WT[(size_t)(n0 + ty + j) * K + k0 + tx] = f2bf(tile[tx][ty + j]);
}

// ---------------- generic bf16 MFMA GEMM ----------------
// C[M,N] = A[M,K] * BT[N,K]^T + bias ; MODE 0: f32 out, 1: bf16 out, 2: bf16 relu out
template <int MODE>
__global__ __launch_bounds__(256) void k_gemm(const u16* __restrict__ A,
                                              const u16* __restrict__ BT,
                                              const float* __restrict__ bias,
                                              void* __restrict__ Cout,
                                              int M, int N, int K) {
    const int w = threadIdx.x >> 6, l = threadIdx.x & 63;
    const int lm = l & 15, lq = l >> 4;
    const int r0 = blockIdx.y * 64 + w * 16;
    const int c0 = blockIdx.x * 64;
    const u16* arow = A + (size_t)(r0 + lm) * K + lq * 8;
    const u16* bp0 = BT + (size_t)(c0 + lm) * K + lq * 8;
    const u16* bp1 = bp0 + (size_t)16 * K;
    const u16* bp2 = bp0 + (size_t)32 * K;
    const u16* bp3 = bp0 + (size_t)48 * K;
    f32x4 acc0 = {0.f, 0.f, 0.f, 0.f}, acc1 = acc0, acc2 = acc0, acc3 = acc0;
    for (int k0 = 0; k0 < K; k0 += 32) {
        short8 a = *(const short8*)(arow + k0);
        acc0 = __builtin_amdgcn_mfma_f32_16x16x32_bf16(a, *(const short8*)(bp0 + k0), acc0, 0, 0, 0);
        acc1 = __builtin_amdgcn_mfma_f32_16x16x32_bf16(a, *(const short8*)(bp1 + k0), acc1, 0, 0, 0);
        acc2 = __builtin_amdgcn_mfma_f32_16x16x32_bf16(a, *(const short8*)(bp2 + k0), acc2, 0, 0, 0);
        acc3 = __builtin_amdgcn_mfma_f32_16x16x32_bf16(a, *(const short8*)(bp3 + k0), acc3, 0, 0, 0);
    }
    f32x4 accs[4] = {acc0, acc1, acc2, acc3};
    #pragma unroll
    for (int nt = 0; nt < 4; nt++) {
        #pragma unroll
        for (int r = 0; r < 4; r++) {
            int row = r0 + lq * 4 + r;          // C/D layout: row=(l>>4)*4+reg
            int col = c0 + nt * 16 + lm;        //             col=l&15
            float v = accs[nt][r] + bias[col];
            if (MODE == 0) {
                ((float*)Cout)[(size_t)row * N + col] = v;
            } else {
                if (MODE == 2) v = fmaxf(v, 0.f);
                ((u16*)Cout)[(size_t)row * N + col] = f2bf(v);
            }
        }
    }
}

// ---------------- LayerNorm + ReLU (row width 1024) ----------------
__global__ __launch_bounds__(256) void k_ln_relu(const float* __restrict__ X,
                                                 const float* __restrict__ scale,
                                                 const float* __restrict__ bias,
                                                 u16* __restrict__ Y) {
    const int N = 1024;
    size_t row = blockIdx.x;
    const float* x = X + row * N;
    float s = 0.f, ss = 0.f;
    float vals[4];
    #pragma unroll
    for (int j = 0; j < 4; j++) {
        float v = x[threadIdx.x + 256 * j];
        vals[j] = v; s += v; ss += v * v;
    }
    #pragma unroll
    for (int o = 32; o > 0; o >>= 1) { s += __shfl_down(s, o); ss += __shfl_down(ss, o); }
    __shared__ float rs[4], rss[4];
    int w = threadIdx.x >> 6;
    if ((threadIdx.x & 63) == 0) { rs[w] = s; rss[w] = ss; }
    __syncthreads();
    __shared__ float smu, sinv;
    if (threadIdx.x == 0) {
        float a = rs[0] + rs[1] + rs[2] + rs[3];
        float bq = rss[0] + rss[1] + rss[2] + rss[3];
        float mu = a * (1.f / N);
        float var = bq * (1.f / N) - mu * mu;
        smu = mu; sinv = rsqrtf(var + 1e-6f);
    }
    __syncthreads();
    float mu = smu, inv = sinv;
    #pragma unroll
    for (int j = 0; j < 4; j++) {
        int i = threadIdx.x + 256 * j;
        float v = (vals[j] - mu) * inv * scale[i] + bias[i];
        Y[row * N + i] = f2bf(fmaxf(v, 0.f));
    }
}

// ---------------- fused 2-layer persistent LSTM scan ----------------
// 256 blocks x 512 threads, 1 block/CU. Blocks 0..127 = layer 0 (step t),
// blocks 128..255 = layer 1 (step t, lagging layer 0 by one publish).
// hs layout: [slot][unit_group g=j>>3][batch][8 units] -- a block's step
// output is one contiguous 1 KB run, stored as 64x dwordx4 sc0/sc1
// write-through (vs 256x 4B before: ~8x fewer coherence-fabric
// transactions; the per-step vmcnt(0) drain was the invariant ~7-10us
// floor across r3-r5 sync variants).
// A-fragments stay lane-linear: MFMA step i reads unit-group g at
// [g*512 + row*8], 64 lanes x 16 B contiguous per load. Plain cached loads
// (L2 serves the 32-block broadcast; lines only read after publish).
// Sync: decoupled per-role flags; wave 0 polls 2-4 slots/lane with __all +
// s_sleep backoff, then __syncthreads releases the block.
#define FBLOCKS 256
__global__ __launch_bounds__(512, 1) void k_lstm_fused(
    const u16* __restrict__ WhT0, const u16* __restrict__ WiT1,
    const u16* __restrict__ WhT1, const u16* __restrict__ Zi0,
    const float* __restrict__ b1v, const float* __restrict__ c0_all,
    u16* __restrict__ hs0, u16* __restrict__ hs1,
    float* __restrict__ out, unsigned* __restrict__ ctr) {
    const int bk = blockIdx.x;
    const int role = bk >> 7;          // 0: layer0, 1: layer1
    const int bkl = bk & 127;
    const int tid = threadIdx.x;
    const int w = tid >> 6, l = tid & 63, lm = l & 15, lq = l >> 4;
    const int kp = w >> 2, rt = w & 3;

    __shared__ u16 whs[65536];          // 128 KB fragment-ordered B
    __shared__ float zbuf[2 * 64 * 33]; // [kp][batch][32 cols]

    // ---- stage B slices in fragment order (linear: dst = whs + f*8)
    {
        const int NI = role ? 32 : 16;
        const int F = role ? 8192 : 4096;
        const int ISH = role ? 5 : 4;
        for (int f = tid; f < F; f += 512) {
            int flm = f & 15, flq = (f >> 4) & 3;
            int fi = (f >> 6) & (NI - 1);
            int rest = f >> (6 + ISH);
            int fg = rest & 1, fkp = (rest >> 1) & 1;
            int lc = fg * 16 + flm;
            int gcolw = (lc >> 3) * 1024 + bkl * 8 + (lc & 7);
            int k = fi * 32 + flq * 8;
            const u16* src = role
                ? ((fkp == 0 ? WiT1 : WhT1) + (size_t)gcolw * 1024 + k)
                : (WhT0 + (size_t)gcolw * 1024 + fkp * 512 + k);
            *(short8*)(whs + (size_t)f * 8) = *(const short8*)src;
        }
    }
    const int u = tid & 7, b = tid >> 3;
    const int gcol = bkl * 8 + u;
    float c = (c0_all + (size_t)role * 65536)[(size_t)b * 1024 + gcol];
    float bi0 = 0.f, bi1 = 0.f, bi2 = 0.f, bi3 = 0.f;
    if (role) {
        bi0 = b1v[gcol]; bi1 = b1v[1024 + gcol];
        bi2 = b1v[2048 + gcol]; bi3 = b1v[3072 + gcol];
    }
    u16* hs_my = role ? hs1 : hs0;
    float* c_out = out + (size_t)role * 65536;
    float* h_out = out + 131072 + (size_t)role * 65536;
    const int lanoff = (lq * 16 + lm) * 8;
    __syncthreads();

    for (int t = 0; t < 128; t++) {
        // ---- dependency wait: wave 0 polls, backoff, block released by barrier
        if (tid < 64) {
            if (!role) {
                if (t > 0) {
                    unsigned need = (unsigned)t;
                    for (;;) {
                        unsigned a0 = __hip_atomic_load(&ctr[tid * 16], __ATOMIC_RELAXED,
                                                        __HIP_MEMORY_SCOPE_AGENT);
                        unsigned a1 = __hip_atomic_load(&ctr[(tid + 64) * 16], __ATOMIC_RELAXED,
                                                        __HIP_MEMORY_SCOPE_AGENT);
                        int ok = (a0 >= need) && (a1 >= need);
                        if (__all(ok)) break;
                        __builtin_amdgcn_s_sleep(1);
                    }
                }
            } else {
                unsigned n0 = (unsigned)(t + 1), n1 = (unsigned)t;
                for (;;) {
                    unsigned a0 = __hip_atomic_load(&ctr[tid * 16], __ATOMIC_RELAXED,
                                                    __HIP_MEMORY_SCOPE_AGENT);
                    unsigned a1 = __hip_atomic_load(&ctr[(tid + 64) * 16], __ATOMIC_RELAXED,
                                                    __HIP_MEMORY_SCOPE_AGENT);
                    unsigned b0 = __hip_atomic_load(&ctr[(tid + 128) * 16], __ATOMIC_RELAXED,
                                                    __HIP_MEMORY_SCOPE_AGENT);
                    unsigned b1 = __hip_atomic_load(&ctr[(tid + 192) * 16], __ATOMIC_RELAXED,
                                                    __HIP_MEMORY_SCOPE_AGENT);
                    int ok = (a0 >= n0) && (a1 >= n0) && (b0 >= n1) && (b1 >= n1);
                    if (__all(ok)) break;
                    __builtin_amdgcn_s_sleep(1);
                }
            }
        }
        __syncthreads();

        u16 zi0v = 0, zi1v = 0, zi2v = 0, zi3v = 0;
        f32x4 acc0 = {0.f, 0.f, 0.f, 0.f}, acc1 = acc0;

        #define STEPF(Ai, i, NI)                                                  \
        {   union { u32x4 q; short8 v; } _a; _a.q = (Ai);                         \
            short8 _b0 = *(const short8*)(bw0 + (i) * 512);                       \
            short8 _b1 = *(const short8*)(bw0 + (NI) * 512 + (i) * 512);          \
            acc0 = __builtin_amdgcn_mfma_f32_16x16x32_bf16(_a.v, _b0, acc0, 0, 0, 0); \
            acc1 = __builtin_amdgcn_mfma_f32_16x16x32_bf16(_a.v, _b1, acc1, 0, 0, 0); }

        if (!role) {
            // Zi prefetch (plain cached loads, in flight during A loads)
            const u16* zi = Zi0 + ((size_t)b * 128 + t) * 4096 + gcol;
            zi0v = zi[0]; zi1v = zi[1024]; zi2v = zi[2048]; zi3v = zi[3072];
            // A: hs0 slot t; MFMA step i reads unit-group g = kp*64 + i*4 + lq
            const u16* arow = hs0 + (size_t)t * 65536
                            + (size_t)(kp * 64 + lq) * 512 + (rt * 16 + lm) * 8;
            const u16* bw0 = whs + kp * 16384 + lanoff;
            u32x4 A0 = ldg16(arow +     0), A1 = ldg16(arow +  2048);
            u32x4 A2 = ldg16(arow +  4096), A3 = ldg16(arow +  6144);
            u32x4 A4 = ldg16(arow +  8192), A5 = ldg16(arow + 10240);
            u32x4 A6 = ldg16(arow + 12288), A7 = ldg16(arow + 14336);
            u32x4 A8 = ldg16(arow + 16384), A9 = ldg16(arow + 18432);
            u32x4 A10 = ldg16(arow + 20480), A11 = ldg16(arow + 22528);
            u32x4 A12 = ldg16(arow + 24576), A13 = ldg16(arow + 26624);
            u32x4 A14 = ldg16(arow + 28672), A15 = ldg16(arow + 30720);
            asm volatile("s_waitcnt vmcnt(8)"
                         : "+v"(A0), "+v"(A1), "+v"(A2), "+v"(A3),
                           "+v"(A4), "+v"(A5), "+v"(A6), "+v"(A7) :: "memory");
            STEPF(A0, 0, 16) STEPF(A1, 1, 16) STEPF(A2, 2, 16) STEPF(A3, 3, 16)
            STEPF(A4, 4, 16) STEPF(A5, 5, 16) STEPF(A6, 6, 16) STEPF(A7, 7, 16)
            asm volatile("s_waitcnt vmcnt(0)"
                         : "+v"(A8), "+v"(A9), "+v"(A10), "+v"(A11),
                           "+v"(A12), "+v"(A13), "+v"(A14), "+v"(A15) :: "memory");
            STEPF(A8, 8, 16) STEPF(A9, 9, 16) STEPF(A10, 10, 16) STEPF(A11, 11, 16)
            STEPF(A12, 12, 16) STEPF(A13, 13, 16) STEPF(A14, 14, 16) STEPF(A15, 15, 16)
        } else {
            // kp=0: A = h0_t (hs0 slot t+1); kp=1: A = h1_{t-1} (hs1 slot t)
            const u16* abase = (kp == 0) ? hs0 + (size_t)(t + 1) * 65536
                                         : hs1 + (size_t)t * 65536;
            const u16* arow = abase + (size_t)lq * 512 + (rt * 16 + lm) * 8;
            const u16* bw0 = whs + kp * 32768 + lanoff;
            u32x4 A0 = ldg16(arow +     0), A1 = ldg16(arow +  2048);
            u32x4 A2 = ldg16(arow +  4096), A3 = ldg16(arow +  6144);
            u32x4 A4 = ldg16(arow +  8192), A5 = ldg16(arow + 10240);
            u32x4 A6 = ldg16(arow + 12288), A7 = ldg16(arow + 14336);
            u32x4 A8 = ldg16(arow + 16384), A9 = ldg16(arow + 18432);
            u32x4 A10 = ldg16(arow + 20480), A11 = ldg16(arow + 22528);
            u32x4 A12 = ldg16(arow + 24576), A13 = ldg16(arow + 26624);
            u32x4 A14 = ldg16(arow + 28672), A15 = ldg16(arow + 30720);
            u32x4 A16 = ldg16(arow + 32768), A17 = ldg16(arow + 34816);
            u32x4 A18 = ldg16(arow + 36864), A19 = ldg16(arow + 38912);
            u32x4 A20 = ldg16(arow + 40960), A21 = ldg16(arow + 43008);
            u32x4 A22 = ldg16(arow + 45056), A23 = ldg16(arow + 47104);
            u32x4 A24 = ldg16(arow + 49152), A25 = ldg16(arow + 51200);
            u32x4 A26 = ldg16(arow + 53248), A27 = ldg16(arow + 55296);
            u32x4 A28 = ldg16(arow + 57344), A29 = ldg16(arow + 59392);
            u32x4 A30 = ldg16(arow + 61440), A31 = ldg16(arow + 63488);
            asm volatile("s_waitcnt vmcnt(24)"
                         : "+v"(A0), "+v"(A1), "+v"(A2), "+v"(A3),
                           "+v"(A4), "+v"(A5), "+v"(A6), "+v"(A7) :: "memory");
            STEPF(A0, 0, 32) STEPF(A1, 1, 32) STEPF(A2, 2, 32) STEPF(A3, 3, 32)
            STEPF(A4, 4, 32) STEPF(A5, 5, 32) STEPF(A6, 6, 32) STEPF(A7, 7, 32)
            asm volatile("s_waitcnt vmcnt(16)"
                         : "+v"(A8), "+v"(A9), "+v"(A10), "+v"(A11),
                           "+v"(A12), "+v"(A13), "+v"(A14), "+v"(A15) :: "memory");
            STEPF(A8, 8, 32) STEPF(A9, 9, 32) STEPF(A10, 10, 32) STEPF(A11, 11, 32)
            STEPF(A12, 12, 32) STEPF(A13, 13, 32) STEPF(A14, 14, 32) STEPF(A15, 15, 32)
            asm volatile("s_waitcnt vmcnt(8)"
                         : "+v"(A16), "+v"(A17), "+v"(A18), "+v"(A19),
                           "+v"(A20), "+v"(A21), "+v"(A22), "+v"(A23) :: "memory");
            STEPF(A16, 16, 32) STEPF(A17, 17, 32) STEPF(A18, 18, 32) STEPF(A19, 19, 32)
            STEPF(A20, 20, 32) STEPF(A21, 21, 32) STEPF(A22, 22, 32) STEPF(A23, 23, 32)
            asm volatile("s_waitcnt vmcnt(0)"
                         : "+v"(A24), "+v"(A25), "+v"(A26), "+v"(A27),
                           "+v"(A28), "+v"(A29), "+v"(A30), "+v"(A31) :: "memory");
            STEPF(A24, 24, 32) STEPF(A25, 25, 32) STEPF(A26, 26, 32) STEPF(A27, 27, 32)
            STEPF(A28, 28, 32) STEPF(A29, 29, 32) STEPF(A30, 30, 32) STEPF(A31, 31, 32)
        }
        #undef STEPF

        // z-tile -> LDS: row = rt*16 + lq*4 + r ; cols lm (grp0), 16+lm (grp1)
        {
            float* zb = zbuf + (size_t)kp * 2112;
            #pragma unroll
            for (int r = 0; r < 4; r++) {
                int row = rt * 16 + lq * 4 + r;
                zb[row * 33 + lm] = acc0[r];
                zb[row * 33 + 16 + lm] = acc1[r];
            }
        }
        __syncthreads();

        // gates: thread (b,u); local col lc = gate*8+u
        {
            const float* z0 = zbuf + (size_t)b * 33;
            const float* z1 = z0 + 2112;
            float gi = z0[u]      + z1[u]      + (role ? bi0 : bf2f(zi0v));
            float gf = z0[8 + u]  + z1[8 + u]  + (role ? bi1 : bf2f(zi1v));
            float gg = z0[16 + u] + z1[16 + u] + (role ? bi2 : bf2f(zi2v));
            float go = z0[24 + u] + z1[24 + u] + (role ? bi3 : bf2f(zi3v));
            gi = fast_sigmoid(gi);
            gf = fast_sigmoid(gf);
            gg = fast_tanh(gg);
            go = fast_sigmoid(go);
            c = gf * c + gi * gg;
            float h = go * fast_tanh(c);
            // pack the batch row's 8 bf16 into one dwordx4; lane u==0 stores
            unsigned hv = (unsigned)f2bf(h);
            int base = l & 56;
            unsigned p0 = __shfl(hv, base + 0, 64) | (__shfl(hv, base + 1, 64) << 16);
            unsigned p1 = __shfl(hv, base + 2, 64) | (__shfl(hv, base + 3, 64) << 16);
            unsigned p2 = __shfl(hv, base + 4, 64) | (__shfl(hv, base + 5, 64) << 16);
            unsigned p3 = __shfl(hv, base + 6, 64) | (__shfl(hv, base + 7, 64) << 16);
            if (u == 0) {
                u32x4 pv = {p0, p1, p2, p3};
                u16* dst = hs_my + (size_t)(t + 1) * 65536 + (size_t)bkl * 512 + b * 8;
                asm volatile("global_store_dwordx4 %0, %1, off sc0 sc1"
                             :: "v"(dst), "v"(pv) : "memory");
            }
            if (t == 127) {
                c_out[(size_t)b * 1024 + gcol] = c;
                h_out[(size_t)b * 1024 + gcol] = h;
            }
        }
        __syncthreads();   // zbuf reuse + vmcnt(0) drain: h stores at coherence point

        // ---- publish arrival (slot per block, 64 B apart)
        if (tid == 0)
            __hip_atomic_store(&ctr[bk * 16], (unsigned)(t + 1), __ATOMIC_RELAXED,
                               __HIP_MEMORY_SCOPE_AGENT);
    }
}

// ---------------- logits: [8192,1024]bf16 @ WoT[32,1024]bf16 + b_out -> f32 ----------------
// A rows are t*64+b ; output index (b*128+t)*32+n
__global__ __launch_bounds__(256) void k_logits(const u16* __restrict__ Pact,
                                                const u16* __restrict__ WoT,
                                                const float* __restrict__ bout,
                                                float* __restrict__ out) {
    int r = blockIdx.x * 8 + (threadIdx.x >> 5);
    int n = threadIdx.x & 31;
    const u16* a = Pact + (size_t)r * 1024;
    const u16* wv = WoT + (size_t)n * 1024;
    float s = 0.f;
    for (int k = 0; k < 1024; k += 8) {
        short8 av = *(const short8*)(a + k);
        short8 wvv = *(const short8*)(wv + k);
        #pragma unroll
        for (int j = 0; j < 8; j++)
            s += bf2f((u16)av[j]) * bf2f((u16)wvv[j]);
    }
    int t = r >> 6, b = r & 63;
    out[((size_t)b * 128 + t) * 32 + n] = s + bout[n];
}

// ---------------- launcher ----------------
extern "C" void kernel_launch(void* const* d_in, const int* in_sizes, int n_in,
                              void* d_out, int out_size, void* d_ws, size_t ws_size,
                              hipStream_t stream) {
    const float* x      = (const float*)d_in[0];
    const float* c0     = (const float*)d_in[1];
    const float* h0     = (const float*)d_in[2];
    const float* W_pre  = (const float*)d_in[3];
    const float* b_pre  = (const float*)d_in[4];
    const float* ln_s   = (const float*)d_in[5];
    const float* ln_b   = (const float*)d_in[6];
    const float* Wi0    = (const float*)d_in[7];
    const float* Wh0    = (const float*)d_in[8];
    const float* b0     = (const float*)d_in[9];
    const float* Wi1    = (const float*)d_in[10];
    const float* Wh1    = (const float*)d_in[11];
    const float* b1     = (const float*)d_in[12];
    const float* W_post = (const float*)d_in[13];
    const float* b_post = (const float*)d_in[14];
    const float* W_out  = (const float*)d_in[15];
    const float* b_out  = (const float*)d_in[16];
    float* out = (float*)d_out;

    char* ws = (char*)d_ws;
    size_t off = 0;
    auto alloc = [&](size_t bytes) {
        void* p = ws + off;
        off += (bytes + 255) & ~(size_t)255;
        return p;
    };
    u16* WTpre  = (u16*)alloc((size_t)1024 * 512 * 2);
    u16* WTi0   = (u16*)alloc((size_t)4096 * 1024 * 2);
    u16* WTh0   = (u16*)alloc((size_t)4096 * 1024 * 2);
    u16* WTi1   = (u16*)alloc((size_t)4096 * 1024 * 2);
    u16* WTh1   = (u16*)alloc((size_t)4096 * 1024 * 2);
    u16* WTpost = (u16*)alloc((size_t)1024 * 1024 * 2);
    u16* WTout  = (u16*)alloc((size_t)32 * 1024 * 2);
    u16* Xb     = (u16*)alloc((size_t)8192 * 512 * 2);
    u16* preact = (u16*)alloc((size_t)8192 * 1024 * 2);
    u16* hs0    = (u16*)alloc((size_t)129 * 65536 * 2);
    u16* hs1    = (u16*)alloc((size_t)129 * 65536 * 2);
    u16* postact= (u16*)alloc((size_t)8192 * 1024 * 2);
    unsigned* ctr = (unsigned*)alloc(32768);
    void* unionreg = alloc((size_t)8192 * 4096 * 2); // Zi0 bf16 / pre_f32 / Hplain
    float* pre_f32 = (float*)unionreg;
    u16* Zi = (u16*)unionreg;

    // init: counters + bf16 conversions
    k_zero<<<32, 256, 0, stream>>>(ctr, 8192);
    k_cvt<<<(8192 * 512) / 256, 256, 0, stream>>>(x, Xb, 8192 * 512);
    k_cvt_h<<<256, 256, 0, stream>>>(h0, hs0);
    k_cvt_h<<<256, 256, 0, stream>>>(h0 + 65536, hs1);

    // weight transpose+convert
    k_transpose<<<dim3(32, 16), 256, 0, stream>>>(W_pre, WTpre, 512, 1024);
    k_transpose<<<dim3(128, 32), 256, 0, stream>>>(Wi0, WTi0, 1024, 4096);
    k_transpose<<<dim3(128, 32), 256, 0, stream>>>(Wh0, WTh0, 1024, 4096);
    k_transpose<<<dim3(128, 32), 256, 0, stream>>>(Wi1, WTi1, 1024, 4096);
    k_transpose<<<dim3(128, 32), 256, 0, stream>>>(Wh1, WTh1, 1024, 4096);
    k_transpose<<<dim3(32, 32), 256, 0, stream>>>(W_post, WTpost, 1024, 1024);
    k_transpose<<<dim3(1, 32), 256, 0, stream>>>(W_out, WTout, 1024, 32);

    // pre: Dense + LN + relu
    k_gemm<0><<<dim3(16, 128), 256, 0, stream>>>(Xb, WTpre, b_pre, pre_f32, 8192, 1024, 512);
    k_ln_relu<<<8192, 256, 0, stream>>>(pre_f32, ln_s, ln_b, preact);

    // Zi0 = preact @ Wi0 + b0  (row = b*128 + t)
    k_gemm<1><<<dim3(64, 128), 256, 0, stream>>>(preact, WTi0, b0, Zi, 8192, 4096, 1024);

    // fused 2-layer pipelined scan
    {
        const u16* WhT0_ = WTh0; const u16* WiT1_ = WTi1; const u16* WhT1_ = WTh1;
        const u16* Zi_ = Zi; const float* b1_ = b1; const float* c0_ = c0;
        u16* hs0_ = hs0; u16* hs1_ = hs1; float* out_ = out; unsigned* ctr_ = ctr;
        void* args[] = {&WhT0_, &WiT1_, &WhT1_, &Zi_, &b1_, &c0_,
                        &hs0_, &hs1_, &out_, &ctr_};
        hipLaunchCooperativeKernel((void*)k_lstm_fused, dim3(FBLOCKS), dim3(512),
                                   args, 0, stream);
    }

    // repack hs1 (scan layout) -> plain [t*64+b][1024] into dead Zi region
    u16* Hplain = Zi;   // Zi dead after scan
    k_repack<<<4096, 256, 0, stream>>>(hs1, Hplain);

    // post Dense+relu, then logits
    k_gemm<2><<<dim3(16, 128), 256, 0, stream>>>(Hplain, WTpost, b_post, postact,
                                                 8192, 1024, 1024);
    k_logits<<<1024, 256, 0, stream>>>(postact, WTout, b_out, out + 262144);
}

// Round 8
// 1165.294 us; speedup vs baseline: 8.2008x; 1.5092x over previous
//
#include <hip/hip_runtime.h>
#include <hip/hip_bf16.h>
#include <math.h>

typedef __attribute__((ext_vector_type(8))) short short8;
typedef __attribute__((ext_vector_type(4))) float f32x4;
typedef __attribute__((ext_vector_type(4))) unsigned u32x4;
typedef unsigned short u16;
typedef unsigned long long u64;

__device__ __forceinline__ u16 f2bf(float f) {
    union { float f; unsigned u; } v; v.f = f;
    unsigned r = v.u + 0x7fffu + ((v.u >> 16) & 1u);   // RNE
    return (u16)(r >> 16);
}
__device__ __forceinline__ float bf2f(u16 b) {
    union { unsigned u; float f; } v; v.u = ((unsigned)b) << 16;
    return v.f;
}
__device__ __forceinline__ float fast_sigmoid(float x) {
    return __builtin_amdgcn_rcpf(1.f + __expf(-x));
}
__device__ __forceinline__ float fast_tanh(float x) {
    return 1.f - 2.f * __builtin_amdgcn_rcpf(1.f + __expf(2.f * x));
}
// cached (L1/L2) pipelined 16-B load; asm so it can't be hoisted above spins.
// Constraint MUST be "=v" (VGPR): "=r" permits SGPR dest -> invalid VMEM.
__device__ __forceinline__ u32x4 ldg16(const void* p) {
    u32x4 r;
    asm volatile("global_load_dwordx4 %0, %1, off"
                 : "=v"(r) : "v"(p) : "memory");
    return r;
}

// ---------------- utility kernels ----------------

__global__ __launch_bounds__(256) void k_zero(unsigned* p, int n) {
    int i = blockIdx.x * 256 + threadIdx.x;
    if (i < n) p[i] = 0u;
}

__global__ __launch_bounds__(256) void k_cvt(const float* __restrict__ in,
                                             u16* __restrict__ out, int n) {
    int i = blockIdx.x * 256 + threadIdx.x;
    if (i < n) out[i] = f2bf(in[i]);
}

// h0 [B=64][H=1024] f32 -> hs slot-0 layout [g=j>>3][b][j&7] bf16
__global__ __launch_bounds__(256) void k_cvt_h(const float* __restrict__ in,
                                               u16* __restrict__ out) {
    int i = blockIdx.x * 256 + threadIdx.x;   // 65536 threads
    int b = i >> 10, j = i & 1023;
    out[(size_t)(j >> 3) * 512 + b * 8 + (j & 7)] = f2bf(in[i]);
}

// W[K][N] f32 -> WT[N][K] bf16
__global__ __launch_bounds__(256) void k_transpose(const float* __restrict__ W,
                                                   u16* __restrict__ WT, int K, int N) {
    __shared__ float tile[32][33];
    int n0 = blockIdx.x * 32, k0 = blockIdx.y * 32;
    int tx = threadIdx.x & 31, ty = threadIdx.x >> 5;
    #pragma unroll
    for (int j = 0; j < 32; j += 8)
        tile[ty + j][tx] = W[(size_t)(k0 + ty + j) * N + n0 + tx];
    __syncthreads();
    #pragma unroll
    for (int j = 0; j < 32; j += 8)
        WT[(size_t)(n0 + ty + j) * K + k0 + tx] = f2bf(tile[tx][ty + j]);
}

// ---------------- generic bf16 MFMA GEMM ----------------
// C[M,N] = A[M,K] * BT[N,K]^T + bias ; MODE 0: f32 out, 1: bf16 out, 2: bf16 relu out
template <int MODE>
__global__ __launch_bounds__(256) void k_gemm(const u16* __restrict__ A,
                                              const u16* __restrict__ BT,
                                              const float* __restrict__ bias,
                                              void* __restrict__ Cout,
                                              int M, int N, int K) {
    const int w = threadIdx.x >> 6, l = threadIdx.x & 63;
    const int lm = l & 15, lq = l >> 4;
    const int r0 = blockIdx.y * 64 + w * 16;
    const int c0 = blockIdx.x * 64;
    const u16* arow = A + (size_t)(r0 + lm) * K + lq * 8;
    const u16* bp0 = BT + (size_t)(c0 + lm) * K + lq * 8;
    const u16* bp1 = bp0 + (size_t)16 * K;
    const u16* bp2 = bp0 + (size_t)32 * K;
    const u16* bp3 = bp0 + (size_t)48 * K;
    f32x4 acc0 = {0.f, 0.f, 0.f, 0.f}, acc1 = acc0, acc2 = acc0, acc3 = acc0;
    for (int k0 = 0; k0 < K; k0 += 32) {
        short8 a = *(const short8*)(arow + k0);
        acc0 = __builtin_amdgcn_mfma_f32_16x16x32_bf16(a, *(const short8*)(bp0 + k0), acc0, 0, 0, 0);
        acc1 = __builtin_amdgcn_mfma_f32_16x16x32_bf16(a, *(const short8*)(bp1 + k0), acc1, 0, 0, 0);
        acc2 = __builtin_amdgcn_mfma_f32_16x16x32_bf16(a, *(const short8*)(bp2 + k0), acc2, 0, 0, 0);
        acc3 = __builtin_amdgcn_mfma_f32_16x16x32_bf16(a, *(const short8*)(bp3 + k0), acc3, 0, 0, 0);
    }
    f32x4 accs[4] = {acc0, acc1, acc2, acc3};
    #pragma unroll
    for (int nt = 0; nt < 4; nt++) {
        #pragma unroll
        for (int r = 0; r < 4; r++) {
            int row = r0 + lq * 4 + r;          // C/D layout: row=(l>>4)*4+reg
            int col = c0 + nt * 16 + lm;        //             col=l&15
            float v = accs[nt][r] + bias[col];
            if (MODE == 0) {
                ((float*)Cout)[(size_t)row * N + col] = v;
            } else {
                if (MODE == 2) v = fmaxf(v, 0.f);
                ((u16*)Cout)[(size_t)row * N + col] = f2bf(v);
            }
        }
    }
}

// ---------------- LayerNorm + ReLU -> scan-layout preact ----------------
// X rows are b*128+t ; output preS[t][g][b][8] bf16
__global__ __launch_bounds__(256) void k_ln_relu(const float* __restrict__ X,
                                                 const float* __restrict__ scale,
                                                 const float* __restrict__ bias,
                                                 u16* __restrict__ preS) {
    const int N = 1024;
    int row = blockIdx.x;
    int b = row >> 7, t = row & 127;
    const float* x = X + (size_t)row * N;
    __shared__ float vbuf[1024];
    float s = 0.f, ss = 0.f;
    float vals[4];
    #pragma unroll
    for (int j = 0; j < 4; j++) {
        float v = x[threadIdx.x + 256 * j];
        vals[j] = v; s += v; ss += v * v;
    }
    #pragma unroll
    for (int o = 32; o > 0; o >>= 1) { s += __shfl_down(s, o); ss += __shfl_down(ss, o); }
    __shared__ float rs[4], rss[4];
    int w = threadIdx.x >> 6;
    if ((threadIdx.x & 63) == 0) { rs[w] = s; rss[w] = ss; }
    __syncthreads();
    __shared__ float smu, sinv;
    if (threadIdx.x == 0) {
        float a = rs[0] + rs[1] + rs[2] + rs[3];
        float bq = rss[0] + rss[1] + rss[2] + rss[3];
        float mu = a * (1.f / N);
        float var = bq * (1.f / N) - mu * mu;
        smu = mu; sinv = rsqrtf(var + 1e-6f);
    }
    __syncthreads();
    float mu = smu, inv = sinv;
    #pragma unroll
    for (int j = 0; j < 4; j++) {
        int i = threadIdx.x + 256 * j;
        float v = (vals[j] - mu) * inv * scale[i] + bias[i];
        vbuf[i] = fmaxf(v, 0.f);
    }
    __syncthreads();
    if (threadIdx.x < 128) {
        int g = threadIdx.x;
        union { u16 h[8]; u32x4 v; } pk;
        #pragma unroll
        for (int e = 0; e < 8; e++) pk.h[e] = f2bf(vbuf[g * 8 + e]);
        *(u32x4*)(preS + (size_t)t * 65536 + (size_t)g * 512 + b * 8) = pk.v;
    }
}

// ---------------- fused symmetric 2-layer persistent LSTM scan ----------------
// 256 blocks x 512 threads, 1 block/CU. Blocks 0..127 = layer 0, 128..255 =
// layer 1 (lagging one publish). BOTH roles compute z = [x_in ; h_prev] @
// [Wi ; Wh] + b with K=2048: Wi|Wh slice (128 KB) LDS-resident in fragment
// order; kp (wave>>2) selects K-half. Role 0: x_in = preact_t (STATIC scan-
// layout buffer, no sync dep), h_prev = hs0[t]. Role 1: x_in = hs0[t+1],
// h_prev = hs1[t]. This folds the former standalone Zi0 GEMM (~68.7 GFLOP)
// into the scan for free (role-1 critical path unchanged).
// hs layout [slot][g][b][8]: block's step output contiguous 1 KB, stored as
// 64x dwordx4 sc0/sc1 write-through (round-7 win). Plain cached A loads.
// Sync: decoupled per-role flags, wave-0 ballot polls + s_sleep backoff.
// Role 1 dual-stores h to Hplain[t*64+b][1024] (plain) for the post-GEMM.
#define FBLOCKS 256
__global__ __launch_bounds__(512, 1) void k_lstm_fused(
    const u16* __restrict__ WiT0, const u16* __restrict__ WhT0,
    const u16* __restrict__ WiT1, const u16* __restrict__ WhT1,
    const u16* __restrict__ preS, const float* __restrict__ b0v,
    const float* __restrict__ b1v, const float* __restrict__ c0_all,
    u16* __restrict__ hs0, u16* __restrict__ hs1, u16* __restrict__ Hp,
    float* __restrict__ out, unsigned* __restrict__ ctr) {
    const int bk = blockIdx.x;
    const int role = bk >> 7;          // 0: layer0, 1: layer1
    const int bkl = bk & 127;
    const int tid = threadIdx.x;
    const int w = tid >> 6, l = tid & 63, lm = l & 15, lq = l >> 4;
    const int kp = w >> 2, rt = w & 3;

    __shared__ u16 whs[65536];          // 128 KB fragment-ordered [Wi;Wh]
    __shared__ float zbuf[2 * 64 * 33]; // [kp][batch][32 cols]

    // ---- stage Wi|Wh slices in fragment order (dst = whs + f*8)
    {
        const u16* Wx = role ? WiT1 : WiT0;
        const u16* Wh = role ? WhT1 : WhT0;
        for (int f = tid; f < 8192; f += 512) {
            int flm = f & 15, flq = (f >> 4) & 3;
            int fi = (f >> 6) & 31;
            int rest = f >> 11;
            int fg = rest & 1, fkp = (rest >> 1) & 1;
            int lc = fg * 16 + flm;
            int gcolw = (lc >> 3) * 1024 + bkl * 8 + (lc & 7);
            int k = fi * 32 + flq * 8;
            const u16* src = (fkp == 0 ? Wx : Wh) + (size_t)gcolw * 1024 + k;
            *(short8*)(whs + (size_t)f * 8) = *(const short8*)src;
        }
    }
    const int u = tid & 7, b = tid >> 3;
    const int gcol = bkl * 8 + u;
    float c = (c0_all + (size_t)role * 65536)[(size_t)b * 1024 + gcol];
    const float* bv = role ? b1v : b0v;
    float bi0 = bv[gcol], bi1 = bv[1024 + gcol];
    float bi2 = bv[2048 + gcol], bi3 = bv[3072 + gcol];
    u16* hs_my = role ? hs1 : hs0;
    float* c_out = out + (size_t)role * 65536;
    float* h_out = out + 131072 + (size_t)role * 65536;
    const int lanoff = (lq * 16 + lm) * 8;
    __syncthreads();

    for (int t = 0; t < 128; t++) {
        // ---- dependency wait: wave 0 polls with backoff, barrier releases
        if (tid < 64) {
            if (!role) {
                if (t > 0) {
                    unsigned need = (unsigned)t;
                    for (;;) {
                        unsigned a0 = __hip_atomic_load(&ctr[tid * 16], __ATOMIC_RELAXED,
                                                        __HIP_MEMORY_SCOPE_AGENT);
                        unsigned a1 = __hip_atomic_load(&ctr[(tid + 64) * 16], __ATOMIC_RELAXED,
                                                        __HIP_MEMORY_SCOPE_AGENT);
                        int ok = (a0 >= need) && (a1 >= need);
                        if (__all(ok)) break;
                        __builtin_amdgcn_s_sleep(1);
                    }
                }
            } else {
                unsigned n0 = (unsigned)(t + 1), n1 = (unsigned)t;
                for (;;) {
                    unsigned a0 = __hip_atomic_load(&ctr[tid * 16], __ATOMIC_RELAXED,
                                                    __HIP_MEMORY_SCOPE_AGENT);
                    unsigned a1 = __hip_atomic_load(&ctr[(tid + 64) * 16], __ATOMIC_RELAXED,
                                                    __HIP_MEMORY_SCOPE_AGENT);
                    unsigned b0 = __hip_atomic_load(&ctr[(tid + 128) * 16], __ATOMIC_RELAXED,
                                                    __HIP_MEMORY_SCOPE_AGENT);
                    unsigned b1 = __hip_atomic_load(&ctr[(tid + 192) * 16], __ATOMIC_RELAXED,
                                                    __HIP_MEMORY_SCOPE_AGENT);
                    int ok = (a0 >= n0) && (a1 >= n0) && (b0 >= n1) && (b1 >= n1);
                    if (__all(ok)) break;
                    __builtin_amdgcn_s_sleep(1);
                }
            }
        }
        __syncthreads();

        // ---- A source for this wave's K-half
        const u16* abase;
        if (!role) abase = (kp == 0) ? preS + (size_t)t * 65536
                                     : hs0 + (size_t)t * 65536;
        else       abase = (kp == 0) ? hs0 + (size_t)(t + 1) * 65536
                                     : hs1 + (size_t)t * 65536;
        const u16* arow = abase + (size_t)lq * 512 + (rt * 16 + lm) * 8;
        const u16* bw0 = whs + kp * 32768 + lanoff;

        f32x4 acc0 = {0.f, 0.f, 0.f, 0.f}, acc1 = acc0;
        #define STEPF(Ai, i)                                                      \
        {   union { u32x4 q; short8 v; } _a; _a.q = (Ai);                         \
            short8 _b0 = *(const short8*)(bw0 + (i) * 512);                       \
            short8 _b1 = *(const short8*)(bw0 + 16384 + (i) * 512);               \
            acc0 = __builtin_amdgcn_mfma_f32_16x16x32_bf16(_a.v, _b0, acc0, 0, 0, 0); \
            acc1 = __builtin_amdgcn_mfma_f32_16x16x32_bf16(_a.v, _b1, acc1, 0, 0, 0); }

        u32x4 A0 = ldg16(arow +     0), A1 = ldg16(arow +  2048);
        u32x4 A2 = ldg16(arow +  4096), A3 = ldg16(arow +  6144);
        u32x4 A4 = ldg16(arow +  8192), A5 = ldg16(arow + 10240);
        u32x4 A6 = ldg16(arow + 12288), A7 = ldg16(arow + 14336);
        u32x4 A8 = ldg16(arow + 16384), A9 = ldg16(arow + 18432);
        u32x4 A10 = ldg16(arow + 20480), A11 = ldg16(arow + 22528);
        u32x4 A12 = ldg16(arow + 24576), A13 = ldg16(arow + 26624);
        u32x4 A14 = ldg16(arow + 28672), A15 = ldg16(arow + 30720);
        u32x4 A16 = ldg16(arow + 32768), A17 = ldg16(arow + 34816);
        u32x4 A18 = ldg16(arow + 36864), A19 = ldg16(arow + 38912);
        u32x4 A20 = ldg16(arow + 40960), A21 = ldg16(arow + 43008);
        u32x4 A22 = ldg16(arow + 45056), A23 = ldg16(arow + 47104);
        u32x4 A24 = ldg16(arow + 49152), A25 = ldg16(arow + 51200);
        u32x4 A26 = ldg16(arow + 53248), A27 = ldg16(arow + 55296);
        u32x4 A28 = ldg16(arow + 57344), A29 = ldg16(arow + 59392);
        u32x4 A30 = ldg16(arow + 61440), A31 = ldg16(arow + 63488);
        asm volatile("s_waitcnt vmcnt(24)"
                     : "+v"(A0), "+v"(A1), "+v"(A2), "+v"(A3),
                       "+v"(A4), "+v"(A5), "+v"(A6), "+v"(A7) :: "memory");
        STEPF(A0, 0) STEPF(A1, 1) STEPF(A2, 2) STEPF(A3, 3)
        STEPF(A4, 4) STEPF(A5, 5) STEPF(A6, 6) STEPF(A7, 7)
        asm volatile("s_waitcnt vmcnt(16)"
                     : "+v"(A8), "+v"(A9), "+v"(A10), "+v"(A11),
                       "+v"(A12), "+v"(A13), "+v"(A14), "+v"(A15) :: "memory");
        STEPF(A8, 8) STEPF(A9, 9) STEPF(A10, 10) STEPF(A11, 11)
        STEPF(A12, 12) STEPF(A13, 13) STEPF(A14, 14) STEPF(A15, 15)
        asm volatile("s_waitcnt vmcnt(8)"
                     : "+v"(A16), "+v"(A17), "+v"(A18), "+v"(A19),
                       "+v"(A20), "+v"(A21), "+v"(A22), "+v"(A23) :: "memory");
        STEPF(A16, 16) STEPF(A17, 17) STEPF(A18, 18) STEPF(A19, 19)
        STEPF(A20, 20) STEPF(A21, 21) STEPF(A22, 22) STEPF(A23, 23)
        asm volatile("s_waitcnt vmcnt(0)"
                     : "+v"(A24), "+v"(A25), "+v"(A26), "+v"(A27),
                       "+v"(A28), "+v"(A29), "+v"(A30), "+v"(A31) :: "memory");
        STEPF(A24, 24) STEPF(A25, 25) STEPF(A26, 26) STEPF(A27, 27)
        STEPF(A28, 28) STEPF(A29, 29) STEPF(A30, 30) STEPF(A31, 31)
        #undef STEPF

        // z-tile -> LDS: row = rt*16 + lq*4 + r ; cols lm (grp0), 16+lm (grp1)
        {
            float* zb = zbuf + (size_t)kp * 2112;
            #pragma unroll
            for (int r = 0; r < 4; r++) {
                int row = rt * 16 + lq * 4 + r;
                zb[row * 33 + lm] = acc0[r];
                zb[row * 33 + 16 + lm] = acc1[r];
            }
        }
        __syncthreads();

        // gates: thread (b,u); local col lc = gate*8+u
        {
            const float* z0 = zbuf + (size_t)b * 33;
            const float* z1 = z0 + 2112;
            float gi = z0[u]      + z1[u]      + bi0;
            float gf = z0[8 + u]  + z1[8 + u]  + bi1;
            float gg = z0[16 + u] + z1[16 + u] + bi2;
            float go = z0[24 + u] + z1[24 + u] + bi3;
            gi = fast_sigmoid(gi);
            gf = fast_sigmoid(gf);
            gg = fast_tanh(gg);
            go = fast_sigmoid(go);
            c = gf * c + gi * gg;
            float h = go * fast_tanh(c);
            // pack batch row's 8 bf16 into one dwordx4; lane u==0 stores
            unsigned hv = (unsigned)f2bf(h);
            int base = l & 56;
            unsigned p0 = __shfl(hv, base + 0, 64) | (__shfl(hv, base + 1, 64) << 16);
            unsigned p1 = __shfl(hv, base + 2, 64) | (__shfl(hv, base + 3, 64) << 16);
            unsigned p2 = __shfl(hv, base + 4, 64) | (__shfl(hv, base + 5, 64) << 16);
            unsigned p3 = __shfl(hv, base + 6, 64) | (__shfl(hv, base + 7, 64) << 16);
            if (u == 0) {
                u32x4 pv = {p0, p1, p2, p3};
                u16* dst = hs_my + (size_t)(t + 1) * 65536 + (size_t)bkl * 512 + b * 8;
                asm volatile("global_store_dwordx4 %0, %1, off sc0 sc1"
                             :: "v"(dst), "v"(pv) : "memory");
                if (role) {   // plain store for the post-GEMM (read after kernel end)
                    u16* d2 = Hp + (size_t)(t * 64 + b) * 1024 + bkl * 8;
                    *(u32x4*)d2 = pv;
                }
            }
            if (t == 127) {
                c_out[(size_t)b * 1024 + gcol] = c;
                h_out[(size_t)b * 1024 + gcol] = h;
            }
        }
        __syncthreads();   // zbuf reuse + vmcnt(0) drain: h stores at coherence point

        // ---- publish arrival (slot per block, 64 B apart)
        if (tid == 0)
            __hip_atomic_store(&ctr[bk * 16], (unsigned)(t + 1), __ATOMIC_RELAXED,
                               __HIP_MEMORY_SCOPE_AGENT);
    }
}

// ---------------- logits: [8192,1024]bf16 @ WoT[32,1024]bf16 + b_out -> f32 ----------------
// A rows are t*64+b ; output index (b*128+t)*32+n
__global__ __launch_bounds__(256) void k_logits(const u16* __restrict__ Pact,
                                                const u16* __restrict__ WoT,
                                                const float* __restrict__ bout,
                                                float* __restrict__ out) {
    int r = blockIdx.x * 8 + (threadIdx.x >> 5);
    int n = threadIdx.x & 31;
    const u16* a = Pact + (size_t)r * 1024;
    const u16* wv = WoT + (size_t)n * 1024;
    float s = 0.f;
    for (int k = 0; k < 1024; k += 8) {
        short8 av = *(const short8*)(a + k);
        short8 wvv = *(const short8*)(wv + k);
        #pragma unroll
        for (int j = 0; j < 8; j++)
            s += bf2f((u16)av[j]) * bf2f((u16)wvv[j]);
    }
    int t = r >> 6, b = r & 63;
    out[((size_t)b * 128 + t) * 32 + n] = s + bout[n];
}

// ---------------- launcher ----------------
extern "C" void kernel_launch(void* const* d_in, const int* in_sizes, int n_in,
                              void* d_out, int out_size, void* d_ws, size_t ws_size,
                              hipStream_t stream) {
    const float* x      = (const float*)d_in[0];
    const float* c0     = (const float*)d_in[1];
    const float* h0     = (const float*)d_in[2];
    const float* W_pre  = (const float*)d_in[3];
    const float* b_pre  = (const float*)d_in[4];
    const float* ln_s   = (const float*)d_in[5];
    const float* ln_b   = (const float*)d_in[6];
    const float* Wi0    = (const float*)d_in[7];
    const float* Wh0    = (const float*)d_in[8];
    const float* b0     = (const float*)d_in[9];
    const float* Wi1    = (const float*)d_in[10];
    const float* Wh1    = (const float*)d_in[11];
    const float* b1     = (const float*)d_in[12];
    const float* W_post = (const float*)d_in[13];
    const float* b_post = (const float*)d_in[14];
    const float* W_out  = (const float*)d_in[15];
    const float* b_out  = (const float*)d_in[16];
    float* out = (float*)d_out;

    char* ws = (char*)d_ws;
    size_t off = 0;
    auto alloc = [&](size_t bytes) {
        void* p = ws + off;
        off += (bytes + 255) & ~(size_t)255;
        return p;
    };
    u16* WTpre  = (u16*)alloc((size_t)1024 * 512 * 2);
    u16* WTi0   = (u16*)alloc((size_t)4096 * 1024 * 2);
    u16* WTh0   = (u16*)alloc((size_t)4096 * 1024 * 2);
    u16* WTi1   = (u16*)alloc((size_t)4096 * 1024 * 2);
    u16* WTh1   = (u16*)alloc((size_t)4096 * 1024 * 2);
    u16* WTpost = (u16*)alloc((size_t)1024 * 1024 * 2);
    u16* WTout  = (u16*)alloc((size_t)32 * 1024 * 2);
    u16* Xb     = (u16*)alloc((size_t)8192 * 512 * 2);
    u16* preS   = (u16*)alloc((size_t)128 * 65536 * 2);   // preact, scan layout
    u16* hs0    = (u16*)alloc((size_t)129 * 65536 * 2);
    u16* hs1    = (u16*)alloc((size_t)129 * 65536 * 2);
    u16* postact= (u16*)alloc((size_t)8192 * 1024 * 2);
    unsigned* ctr = (unsigned*)alloc(32768);
    void* unionreg = alloc((size_t)8192 * 4096 * 2); // pre_f32 (32MB) / Hplain (16MB)
    float* pre_f32 = (float*)unionreg;
    u16* Hplain = (u16*)unionreg;

    // init: counters + bf16 conversions
    k_zero<<<32, 256, 0, stream>>>(ctr, 8192);
    k_cvt<<<(8192 * 512) / 256, 256, 0, stream>>>(x, Xb, 8192 * 512);
    k_cvt_h<<<256, 256, 0, stream>>>(h0, hs0);
    k_cvt_h<<<256, 256, 0, stream>>>(h0 + 65536, hs1);

    // weight transpose+convert
    k_transpose<<<dim3(32, 16), 256, 0, stream>>>(W_pre, WTpre, 512, 1024);
    k_transpose<<<dim3(128, 32), 256, 0, stream>>>(Wi0, WTi0, 1024, 4096);
    k_transpose<<<dim3(128, 32), 256, 0, stream>>>(Wh0, WTh0, 1024, 4096);
    k_transpose<<<dim3(128, 32), 256, 0, stream>>>(Wi1, WTi1, 1024, 4096);
    k_transpose<<<dim3(128, 32), 256, 0, stream>>>(Wh1, WTh1, 1024, 4096);
    k_transpose<<<dim3(32, 32), 256, 0, stream>>>(W_post, WTpost, 1024, 1024);
    k_transpose<<<dim3(1, 32), 256, 0, stream>>>(W_out, WTout, 1024, 32);

    // pre: Dense + LN + relu (-> scan-layout preS)
    k_gemm<0><<<dim3(16, 128), 256, 0, stream>>>(Xb, WTpre, b_pre, pre_f32, 8192, 1024, 512);
    k_ln_relu<<<8192, 256, 0, stream>>>(pre_f32, ln_s, ln_b, preS);

    // fused symmetric 2-layer pipelined scan (Zi0 GEMM folded in)
    {
        const u16* WiT0_ = WTi0; const u16* WhT0_ = WTh0;
        const u16* WiT1_ = WTi1; const u16* WhT1_ = WTh1;
        const u16* preS_ = preS; const float* b0_ = b0; const float* b1_ = b1;
        const float* c0_ = c0; u16* hs0_ = hs0; u16* hs1_ = hs1;
        u16* Hp_ = Hplain; float* out_ = out; unsigned* ctr_ = ctr;
        void* args[] = {&WiT0_, &WhT0_, &WiT1_, &WhT1_, &preS_, &b0_, &b1_,
                        &c0_, &hs0_, &hs1_, &Hp_, &out_, &ctr_};
        hipLaunchCooperativeKernel((void*)k_lstm_fused, dim3(FBLOCKS), dim3(512),
                                   args, 0, stream);
    }

    // post Dense+relu, then logits
    k_gemm<2><<<dim3(16, 128), 256, 0, stream>>>(Hplain, WTpost, b_post, postact,
                                                 8192, 1024, 1024);
    k_logits<<<1024, 256, 0, stream>>>(postact, WTout, b_out, out + 262144);
}